// Round 10
// baseline (531.490 us; speedup 1.0000x reference)
//
#include <hip/hip_runtime.h>
#include <math.h>

#define N_NODES 50000
#define E_TRAIN 800000
#define E_POS 200000
#define E_NEG 200000

// ---------------- degree / CSR build ----------------

__global__ void count_kernel(const int* __restrict__ dst, int* __restrict__ cnt, int e) {
    int i = blockIdx.x * blockDim.x + threadIdx.x;
    if (i < e) atomicAdd(&cnt[dst[i]], 1);
}

__global__ void dis_kernel(const int* __restrict__ cnt, float* __restrict__ dis, int n) {
    int i = blockIdx.x * blockDim.x + threadIdx.x;
    if (i < n) dis[i] = 1.0f / sqrtf((float)(cnt[i] + 1));  // +1 self loop, deg>=1
}

__global__ void scan1_kernel(const int* __restrict__ cnt, int* __restrict__ offs,
                             int* __restrict__ bsum, int n) {
    __shared__ int s[256];
    int i = blockIdx.x * 256 + threadIdx.x;
    int c = (i < n) ? cnt[i] : 0;
    s[threadIdx.x] = c;
    __syncthreads();
    for (int d = 1; d < 256; d <<= 1) {
        int t = 0;
        if ((int)threadIdx.x >= d) t = s[threadIdx.x - d];
        __syncthreads();
        if ((int)threadIdx.x >= d) s[threadIdx.x] += t;
        __syncthreads();
    }
    if (i < n) offs[i] = s[threadIdx.x] - c;  // exclusive
    if (threadIdx.x == 255) bsum[blockIdx.x] = s[255];
}

__global__ void scan2_kernel(int* __restrict__ bsum, int nb) {
    __shared__ int s[256];
    int t = threadIdx.x;
    int v = (t < nb) ? bsum[t] : 0;
    s[t] = v;
    __syncthreads();
    for (int d = 1; d < 256; d <<= 1) {
        int u = 0;
        if (t >= d) u = s[t - d];
        __syncthreads();
        if (t >= d) s[t] += u;
        __syncthreads();
    }
    if (t < nb) bsum[t] = s[t] - v;  // exclusive
}

__global__ void scan3_kernel(int* __restrict__ offs, const int* __restrict__ bsum,
                             int* __restrict__ cursor, int n) {
    int i = blockIdx.x * 256 + threadIdx.x;   // blockDim must be 256
    if (i < n) { int o = offs[i] + bsum[i >> 8]; offs[i] = o; cursor[i] = o; }
}

__global__ void fill_kernel(const int* __restrict__ src, const int* __restrict__ dst,
                            int* __restrict__ cursor, int* __restrict__ csr_src, int e) {
    int i = blockIdx.x * blockDim.x + threadIdx.x;
    if (i < e) {
        int p = atomicAdd(&cursor[dst[i]], 1);
        csr_src[p] = src[i];
    }
}

// ---------------- split-bf16 helpers ----------------

__device__ inline void split_bf16(float f, short& h, short& l) {
    unsigned u = __float_as_uint(f);
    h = (short)(u >> 16);
    float rem = f - __uint_as_float(u & 0xFFFF0000u);
    l = (short)(__float_as_uint(rem) >> 16);
}

// W -> transposed hi/lo bf16: Wt[n*K + k] from W[k*N + n]. Tiny, once per call.
__global__ void wsplit_kernel(const float* __restrict__ W,
                              short* __restrict__ Wt_hi, short* __restrict__ Wt_lo,
                              int K, int N) {
    int i = blockIdx.x * blockDim.x + threadIdx.x;
    if (i >= K * N) return;
    int k = i / N, n = i - k * N;
    short h, l;
    split_bf16(W[i], h, l);
    Wt_hi[(size_t)n * K + k] = h;
    Wt_lo[(size_t)n * K + k] = l;
}

// ---------------- streaming MFMA GEMM (split-bf16, barrier-free) ----------------
// 256 threads = 4 INDEPENDENT waves; wave owns 16 rows x BN cols (acc[BN/16] f32x4).
// No __syncthreads anywhere. A: global->reg (8 fp32/lane/k-tile), split in-reg.
// B: pre-split Wt[n][k] (L2-resident), int4 frag loads per ni per k-tile.
// 3 MFMAs per tile (hi*hi + lo*hi + hi*lo). Epilogue: per-wave LDS transpose ->
// each store covers 4 rows x 256B contiguous (no partial-line write amplification).
// Requires: BN % 64 == 0, K % 32 == 0. C row stride = ldc (N may exceed BN).

typedef short bf16x8 __attribute__((ext_vector_type(8)));
typedef float f32x4 __attribute__((ext_vector_type(4)));

template<int BN, bool BR>
__global__ __launch_bounds__(256) void gemm_stream_kernel(
        const float* __restrict__ A,
        const short* __restrict__ Bth, const short* __restrict__ Btl,
        const float* __restrict__ bias, float* __restrict__ C,
        int M, int K, int ldc) {
    constexpr int NI = BN / 16;
    __shared__ float tr[4][16][68];    // per-wave transpose buffer (wave-local use only)
    int tid = threadIdx.x;
    int lane = tid & 63;
    int wv = tid >> 6;
    int brow = blockIdx.x * 64 + wv * 16;
    int bcol = blockIdx.y * BN;
    int m_lane = lane & 15;
    int kgrp = lane >> 4;              // 0..3

    int arow = brow + m_lane;
    if (arow >= M) arow = M - 1;       // clamp: values discarded by store guard
    const float* Ap = &A[(size_t)arow * K + kgrp * 8];
    const short* Bhp = &Bth[(size_t)(bcol + m_lane) * K + kgrp * 8];
    const short* Blp = &Btl[(size_t)(bcol + m_lane) * K + kgrp * 8];

    f32x4 acc[NI];
    #pragma unroll
    for (int i = 0; i < NI; i++) acc[i] = (f32x4){0.f, 0.f, 0.f, 0.f};

    for (int k0 = 0; k0 < K; k0 += 32) {
        float4 a0 = *(const float4*)&Ap[k0];
        float4 a1 = *(const float4*)&Ap[k0 + 4];
        bf16x8 ah, al;
        {
            short h, l;
            split_bf16(a0.x, h, l); ah[0] = h; al[0] = l;
            split_bf16(a0.y, h, l); ah[1] = h; al[1] = l;
            split_bf16(a0.z, h, l); ah[2] = h; al[2] = l;
            split_bf16(a0.w, h, l); ah[3] = h; al[3] = l;
            split_bf16(a1.x, h, l); ah[4] = h; al[4] = l;
            split_bf16(a1.y, h, l); ah[5] = h; al[5] = l;
            split_bf16(a1.z, h, l); ah[6] = h; al[6] = l;
            split_bf16(a1.w, h, l); ah[7] = h; al[7] = l;
        }
        #pragma unroll
        for (int ni = 0; ni < NI; ni++) {
            size_t o = (size_t)ni * 16 * K + k0;
            bf16x8 bh = *(const bf16x8*)&Bhp[o];
            bf16x8 bl = *(const bf16x8*)&Blp[o];
            acc[ni] = __builtin_amdgcn_mfma_f32_16x16x32_bf16(ah, bh, acc[ni], 0, 0, 0);
            acc[ni] = __builtin_amdgcn_mfma_f32_16x16x32_bf16(al, bh, acc[ni], 0, 0, 0);
            acc[ni] = __builtin_amdgcn_mfma_f32_16x16x32_bf16(ah, bl, acc[ni], 0, 0, 0);
        }
    }

    // epilogue: chunks of 4 ni (64 cols). acc layout: col = ni*16 + m_lane,
    // row(local) = kgrp*4 + reg. Transpose via wave-local LDS, then coalesced float4.
    #pragma unroll
    for (int c = 0; c < NI / 4; c++) {
        #pragma unroll
        for (int q = 0; q < 4; q++) {
            int ni = c * 4 + q;
            float bb = 0.f;
            if (BR) bb = bias[bcol + ni * 16 + m_lane];
            #pragma unroll
            for (int reg = 0; reg < 4; reg++) {
                float v = acc[ni][reg];
                if (BR) v = fmaxf(v + bb, 0.f);
                tr[wv][kgrp * 4 + reg][q * 16 + m_lane] = v;
            }
        }
        // same-wave LDS RAW: compiler inserts lgkmcnt wait; no barrier needed
        #pragma unroll
        for (int j = 0; j < 4; j++) {
            int r = (lane >> 4) + j * 4;       // 4 rows per instruction
            int g = lane & 15;                 // 16 float4 per row = 256B contiguous
            float4 v = *(const float4*)&tr[wv][r][g * 4];
            int row = brow + r;
            if (row < M)
                *(float4*)&C[(size_t)row * ldc + bcol + c * 64 + g * 4] = v;
        }
    }
}

// ---------------- aggregation: out[v] = sum_in h[u]*dis[u]*dis[v] + h[v]*dis[v]^2 (+ b, relu) ----
// R6 version: one wave per node, lane holds VPT consecutive floats; 8-edge batch ILP.

template<int F, bool RELU, bool BIAS>
__global__ void aggregate_kernel(const float* __restrict__ xw,
                                 float* __restrict__ out,
                                 const float* __restrict__ dis,
                                 const int* __restrict__ starts,
                                 const int* __restrict__ ends,
                                 const int* __restrict__ csr_src,
                                 const float* __restrict__ bias,
                                 int n) {
    int wave = (blockIdx.x * blockDim.x + threadIdx.x) >> 6;
    int lane = threadIdx.x & 63;
    if (wave >= n) return;
    int v = wave;
    constexpr int VPT = F / 64;
    float dv = dis[v];
    float acc[VPT];
    {
        const float* r = &xw[(size_t)v * F + lane * VPT];
        #pragma unroll
        for (int i = 0; i < VPT; i++) acc[i] = r[i] * dv * dv;
    }
    int s = starts[v], e = ends[v];
    int p = s;
    for (; p + 8 <= e; p += 8) {
        int u[8];
        #pragma unroll
        for (int q = 0; q < 8; q++) u[q] = csr_src[p + q];
        float w[8];
        #pragma unroll
        for (int q = 0; q < 8; q++) w[q] = dis[u[q]] * dv;
        if constexpr (VPT == 2) {
            float2 g[8];
            #pragma unroll
            for (int q = 0; q < 8; q++)
                g[q] = *(const float2*)&xw[(size_t)u[q] * F + lane * 2];
            #pragma unroll
            for (int q = 0; q < 8; q++) {
                acc[0] += g[q].x * w[q];
                acc[1] += g[q].y * w[q];
            }
        } else {
            float g[8];
            #pragma unroll
            for (int q = 0; q < 8; q++)
                g[q] = xw[(size_t)u[q] * F + lane];
            #pragma unroll
            for (int q = 0; q < 8; q++) acc[0] += g[q] * w[q];
        }
    }
    for (; p < e; p++) {
        int u = csr_src[p];
        float w = dis[u] * dv;
        const float* r = &xw[(size_t)u * F + lane * VPT];
        #pragma unroll
        for (int i = 0; i < VPT; i++) acc[i] += r[i] * w;
    }
    {
        float* o = &out[(size_t)v * F + lane * VPT];
        #pragma unroll
        for (int i = 0; i < VPT; i++) {
            float r = acc[i];
            if (BIAS) r += bias[lane * VPT + i];
            if (RELU) r = fmaxf(r, 0.f);
            o[i] = r;
        }
    }
}

// ---------------- edge dot products: out[e] = h[i0] . h[i1], F=64 ----------------

__global__ void dot_kernel(const float* __restrict__ h,
                           const int* __restrict__ pos, const int* __restrict__ neg,
                           float* __restrict__ out) {
    int t = blockIdx.x * blockDim.x + threadIdx.x;
    if (t >= E_POS + E_NEG) return;
    int i0, i1;
    if (t < E_POS) { i0 = pos[t]; i1 = pos[E_POS + t]; }
    else { int e = t - E_POS; i0 = neg[e]; i1 = neg[E_NEG + e]; }
    const float4* a = (const float4*)&h[(size_t)i0 * 64];
    const float4* b = (const float4*)&h[(size_t)i1 * 64];
    float s0 = 0.f, s1 = 0.f, s2 = 0.f, s3 = 0.f;
    #pragma unroll
    for (int k = 0; k < 16; k += 4) {
        float4 a0 = a[k + 0], a1 = a[k + 1], a2 = a[k + 2], a3 = a[k + 3];
        float4 b0 = b[k + 0], b1 = b[k + 1], b2 = b[k + 2], b3 = b[k + 3];
        s0 += a0.x * b0.x + a0.y * b0.y + a0.z * b0.z + a0.w * b0.w;
        s1 += a1.x * b1.x + a1.y * b1.y + a1.z * b1.z + a1.w * b1.w;
        s2 += a2.x * b2.x + a2.y * b2.y + a2.z * b2.z + a2.w * b2.w;
        s3 += a3.x * b3.x + a3.y * b3.y + a3.z * b3.z + a3.w * b3.w;
    }
    out[t] = (s0 + s1) + (s2 + s3);
}

// ---------------- launch ----------------

extern "C" void kernel_launch(void* const* d_in, const int* in_sizes, int n_in,
                              void* d_out, int out_size, void* d_ws, size_t ws_size,
                              hipStream_t stream) {
    const float* x  = (const float*)d_in[0];
    const int* tei  = (const int*)d_in[1];
    const int* pos  = (const int*)d_in[2];
    const int* neg  = (const int*)d_in[3];
    const float* W1 = (const float*)d_in[4];
    const float* b1 = (const float*)d_in[5];
    const float* W2 = (const float*)d_in[6];
    const float* b2 = (const float*)d_in[7];
    const float* W3 = (const float*)d_in[8];
    const float* b3 = (const float*)d_in[9];
    float* out = (float*)d_out;

    const int* src = tei;
    const int* dst = tei + E_TRAIN;

    char* ws = (char*)d_ws;
    size_t off = 0;
    auto alloc = [&](size_t bytes) -> void* {
        void* p = ws + off;
        off = (off + bytes + 255) & ~(size_t)255;
        return p;
    };
    float* bufA = (float*)alloc((size_t)N_NODES * 128 * 4);  // aggX / xw2 / xw3
    float* bufB = (float*)alloc((size_t)N_NODES * 256 * 4);  // h1, later h3
    float* bufC = (float*)alloc((size_t)N_NODES * 128 * 4);  // h2
    float* dis  = (float*)alloc(N_NODES * 4);
    int* cnt    = (int*)alloc(N_NODES * 4);
    int* offs   = (int*)alloc(N_NODES * 4);
    int* cursor = (int*)alloc(N_NODES * 4);
    int* bsum   = (int*)alloc(256 * 4);
    int* csr    = (int*)alloc((size_t)E_TRAIN * 4);
    short* Wt1h = (short*)alloc((size_t)128 * 256 * 2);
    short* Wt1l = (short*)alloc((size_t)128 * 256 * 2);
    short* Wt2h = (short*)alloc((size_t)256 * 128 * 2);
    short* Wt2l = (short*)alloc((size_t)256 * 128 * 2);
    short* Wt3h = (short*)alloc((size_t)128 * 64 * 2);
    short* Wt3l = (short*)alloc((size_t)128 * 64 * 2);
    (void)ws_size; (void)n_in; (void)in_sizes; (void)out_size;

    hipMemsetAsync(cnt, 0, N_NODES * 4, stream);
    count_kernel<<<(E_TRAIN + 255) / 256, 256, 0, stream>>>(dst, cnt, E_TRAIN);
    dis_kernel<<<(N_NODES + 255) / 256, 256, 0, stream>>>(cnt, dis, N_NODES);
    int nb = (N_NODES + 255) / 256;  // 196
    scan1_kernel<<<nb, 256, 0, stream>>>(cnt, offs, bsum, N_NODES);
    scan2_kernel<<<1, 256, 0, stream>>>(bsum, nb);
    scan3_kernel<<<nb, 256, 0, stream>>>(offs, bsum, cursor, N_NODES);
    fill_kernel<<<(E_TRAIN + 255) / 256, 256, 0, stream>>>(src, dst, cursor, csr, E_TRAIN);
    // after fill: offs[v] = start, cursor[v] = end

    wsplit_kernel<<<(128 * 256 + 255) / 256, 256, 0, stream>>>(W1, Wt1h, Wt1l, 128, 256);
    wsplit_kernel<<<(256 * 128 + 255) / 256, 256, 0, stream>>>(W2, Wt2h, Wt2l, 256, 128);
    wsplit_kernel<<<(128 * 64 + 255) / 256, 256, 0, stream>>>(W3, Wt3h, Wt3l, 128, 64);

    const int GB = (N_NODES + 63) / 64;       // 782 row blocks (64 rows each)
    const int AGG_BLOCKS = (N_NODES + 3) / 4; // 4 waves/block, 1 node/wave

    // layer 1 (agg-first): aggX = agg(x) [F=128]; h1 = relu(aggX @ W1 + b1) [256]
    aggregate_kernel<128, false, false><<<AGG_BLOCKS, 256, 0, stream>>>(
        x, bufA, dis, offs, cursor, csr, nullptr, N_NODES);
    gemm_stream_kernel<128, true><<<dim3(GB, 2), 256, 0, stream>>>(
        bufA, Wt1h, Wt1l, b1, bufB, N_NODES, 128, 256);

    // layer 2 (gemm-first): xw2 = h1 @ W2 [128]; h2 = relu(agg(xw2) + b2)
    gemm_stream_kernel<128, false><<<dim3(GB, 1), 256, 0, stream>>>(
        bufB, Wt2h, Wt2l, nullptr, bufA, N_NODES, 256, 128);
    aggregate_kernel<128, true, true><<<AGG_BLOCKS, 256, 0, stream>>>(
        bufA, bufC, dis, offs, cursor, csr, b2, N_NODES);

    // layer 3 (gemm-first): xw3 = h2 @ W3 [64]; h3 = agg(xw3) + b3
    gemm_stream_kernel<64, false><<<dim3(GB, 1), 256, 0, stream>>>(
        bufC, Wt3h, Wt3l, nullptr, bufA, N_NODES, 128, 64);
    aggregate_kernel<64, false, true><<<AGG_BLOCKS, 256, 0, stream>>>(
        bufA, bufB, dis, offs, cursor, csr, b3, N_NODES);

    // edge dots over h3 (64 features)
    dot_kernel<<<(E_POS + E_NEG + 255) / 256, 256, 0, stream>>>(bufB, pos, neg, out);
}

// Round 11
// 444.661 us; speedup vs baseline: 1.1953x; 1.1953x over previous
//
#include <hip/hip_runtime.h>
#include <math.h>

#define N_NODES 50000
#define E_TRAIN 800000
#define E_POS 200000
#define E_NEG 200000

// ---------------- degree / CSR build ----------------

__global__ void count_kernel(const int* __restrict__ dst, int* __restrict__ cnt, int e) {
    int i = blockIdx.x * blockDim.x + threadIdx.x;
    if (i < e) atomicAdd(&cnt[dst[i]], 1);
}

// scan1 + dis fused: block-level exclusive scan of cnt, plus dis = rsqrt(deg+1)
__global__ void scan1_kernel(const int* __restrict__ cnt, int* __restrict__ offs,
                             int* __restrict__ bsum, float* __restrict__ dis, int n) {
    __shared__ int s[256];
    int i = blockIdx.x * 256 + threadIdx.x;
    int c = (i < n) ? cnt[i] : 0;
    if (i < n) dis[i] = 1.0f / sqrtf((float)(c + 1));  // +1 self loop
    s[threadIdx.x] = c;
    __syncthreads();
    for (int d = 1; d < 256; d <<= 1) {
        int t = 0;
        if ((int)threadIdx.x >= d) t = s[threadIdx.x - d];
        __syncthreads();
        if ((int)threadIdx.x >= d) s[threadIdx.x] += t;
        __syncthreads();
    }
    if (i < n) offs[i] = s[threadIdx.x] - c;  // exclusive
    if (threadIdx.x == 255) bsum[blockIdx.x] = s[255];
}

__global__ void scan2_kernel(int* __restrict__ bsum, int nb) {
    __shared__ int s[256];
    int t = threadIdx.x;
    int v = (t < nb) ? bsum[t] : 0;
    s[t] = v;
    __syncthreads();
    for (int d = 1; d < 256; d <<= 1) {
        int u = 0;
        if (t >= d) u = s[t - d];
        __syncthreads();
        if (t >= d) s[t] += u;
        __syncthreads();
    }
    if (t < nb) bsum[t] = s[t] - v;  // exclusive
}

__global__ void scan3_kernel(int* __restrict__ offs, const int* __restrict__ bsum,
                             int* __restrict__ cursor, int n) {
    int i = blockIdx.x * 256 + threadIdx.x;   // blockDim must be 256
    if (i < n) { int o = offs[i] + bsum[i >> 8]; offs[i] = o; cursor[i] = o; }
}

__global__ void fill_kernel(const int* __restrict__ src, const int* __restrict__ dst,
                            int* __restrict__ cursor, int* __restrict__ csr_src, int e) {
    int i = blockIdx.x * blockDim.x + threadIdx.x;
    if (i < e) {
        int p = atomicAdd(&cursor[dst[i]], 1);
        csr_src[p] = src[i];
    }
}

// ---------------- split-bf16 helpers ----------------

__device__ inline void split_bf16(float f, short& h, short& l) {
    unsigned u = __float_as_uint(f);
    h = (short)(u >> 16);
    float rem = f - __uint_as_float(u & 0xFFFF0000u);
    l = (short)(__float_as_uint(rem) >> 16);
}

// all three weights -> transposed hi/lo bf16 in one launch
__global__ void wsplit_all_kernel(const float* __restrict__ W1, short* __restrict__ W1h, short* __restrict__ W1l,
                                  const float* __restrict__ W2, short* __restrict__ W2h, short* __restrict__ W2l,
                                  const float* __restrict__ W3, short* __restrict__ W3h, short* __restrict__ W3l) {
    int i = blockIdx.x * blockDim.x + threadIdx.x;
    const float* W; short *Wh, *Wl; int K, N;
    if (i < 128 * 256) { W = W1; Wh = W1h; Wl = W1l; K = 128; N = 256; }
    else if (i < 128 * 256 + 256 * 128) { i -= 128 * 256; W = W2; Wh = W2h; Wl = W2l; K = 256; N = 128; }
    else if (i < 128 * 256 + 256 * 128 + 128 * 64) { i -= 128 * 256 + 256 * 128; W = W3; Wh = W3h; Wl = W3l; K = 128; N = 64; }
    else return;
    int k = i / N, n = i - k * N;
    short h, l;
    split_bf16(W[i], h, l);
    Wh[(size_t)n * K + k] = h;
    Wl[(size_t)n * K + k] = l;
}

// ---------------- MFMA GEMM: 512 threads, 128 rows x full N, A streamed, B in LDS ----------------
// 8 waves; wave wv owns rows wv*16..wv*16+15 x all BN cols (acc[BN/16] f32x4).
// A: per-lane global loads (row m_lane within wave tile, 8-k chunk kgrp), split in-reg.
// B: pre-split Wt[n][k] cooperatively staged per 32-k tile (hi/lo, stride 40 shorts),
//    register-prefetch of next tile overlaps MFMA phase.
// Epilogue: per-wave LDS transpose (aliased over B buffer after final barrier) ->
// 256B-contiguous float4 row stores, no partial-line write amplification.
// Requires: K % 32 == 0. M guarded. BR: fused bias+relu.

typedef short bf16x8 __attribute__((ext_vector_type(8)));
typedef float f32x4 __attribute__((ext_vector_type(4)));

template<int BN, bool BR>
__global__ __launch_bounds__(512) void gemm_fulln_kernel(
        const float* __restrict__ A,
        const short* __restrict__ Bth, const short* __restrict__ Btl,
        const float* __restrict__ bias, float* __restrict__ C,
        int M, int K) {
    constexpr int NI = BN / 16;              // 16x16 tiles per wave
    constexpr int BCH = BN * 4;              // int4 chunks per B array per k-tile
    constexpr int BP = (BCH + 511) / 512;    // chunks per thread
    constexpr size_t BSZ = (size_t)2 * BN * 40 * 2;   // hi+lo, stride 40 shorts
    constexpr size_t TSZ = (size_t)8 * 16 * 68 * 4;   // 8-wave transpose buffer
    __shared__ __align__(16) char smem[BSZ > TSZ ? BSZ : TSZ];
    short* Bhi = (short*)smem;
    short* Blo = (short*)(smem + (size_t)BN * 40 * 2);
    float* tr  = (float*)smem;               // aliased after final barrier

    int tid = threadIdx.x;
    int lane = tid & 63;
    int wv = tid >> 6;                       // 0..7
    int brow = blockIdx.x * 128;
    int m_lane = lane & 15;
    int kgrp = lane >> 4;                    // 0..3

    int myrow = brow + wv * 16 + m_lane;
    if (myrow >= M) myrow = M - 1;           // clamp; garbage rows discarded at store
    const float* Ap = &A[(size_t)myrow * K + kgrp * 8];

    f32x4 acc[NI];
    #pragma unroll
    for (int i = 0; i < NI; i++) acc[i] = (f32x4){0.f, 0.f, 0.f, 0.f};

    int4 bhReg[BP], blReg[BP];
    float4 aN0, aN1, aC0, aC1;

    auto loadB = [&](int k0) {
        #pragma unroll
        for (int p = 0; p < BP; p++) {
            int idx = p * 512 + tid;
            if (idx < BCH) {
                int col = idx >> 2;
                int kc = idx & 3;
                size_t o = (size_t)col * K + k0 + kc * 8;
                bhReg[p] = *(const int4*)&Bth[o];
                blReg[p] = *(const int4*)&Btl[o];
            }
        }
    };
    auto loadA = [&](int k0) {
        aN0 = *(const float4*)&Ap[k0];
        aN1 = *(const float4*)&Ap[k0 + 4];
    };

    loadB(0); loadA(0);

    for (int k0 = 0; k0 < K; k0 += 32) {
        aC0 = aN0; aC1 = aN1;
        #pragma unroll
        for (int p = 0; p < BP; p++) {
            int idx = p * 512 + tid;
            if (idx < BCH) {
                int col = idx >> 2;
                int kc = idx & 3;
                *(int4*)&Bhi[col * 40 + kc * 8] = bhReg[p];
                *(int4*)&Blo[col * 40 + kc * 8] = blReg[p];
            }
        }
        __syncthreads();

        if (k0 + 32 < K) { loadB(k0 + 32); loadA(k0 + 32); }  // overlaps MFMA phase

        bf16x8 ah, al;
        {
            short h, l;
            split_bf16(aC0.x, h, l); ah[0] = h; al[0] = l;
            split_bf16(aC0.y, h, l); ah[1] = h; al[1] = l;
            split_bf16(aC0.z, h, l); ah[2] = h; al[2] = l;
            split_bf16(aC0.w, h, l); ah[3] = h; al[3] = l;
            split_bf16(aC1.x, h, l); ah[4] = h; al[4] = l;
            split_bf16(aC1.y, h, l); ah[5] = h; al[5] = l;
            split_bf16(aC1.z, h, l); ah[6] = h; al[6] = l;
            split_bf16(aC1.w, h, l); ah[7] = h; al[7] = l;
        }
        #pragma unroll
        for (int ni = 0; ni < NI; ni++) {
            int boff = (ni * 16 + m_lane) * 40 + kgrp * 8;
            bf16x8 bh = *(const bf16x8*)&Bhi[boff];
            bf16x8 bl = *(const bf16x8*)&Blo[boff];
            acc[ni] = __builtin_amdgcn_mfma_f32_16x16x32_bf16(ah, bh, acc[ni], 0, 0, 0);
            acc[ni] = __builtin_amdgcn_mfma_f32_16x16x32_bf16(al, bh, acc[ni], 0, 0, 0);
            acc[ni] = __builtin_amdgcn_mfma_f32_16x16x32_bf16(ah, bl, acc[ni], 0, 0, 0);
        }
        __syncthreads();
    }

    // epilogue: acc col = ni*16 + m_lane, local row = kgrp*4 + reg.
    // Chunks of 4 ni (64 cols): wave-local LDS transpose, then coalesced float4 stores.
    #pragma unroll
    for (int c = 0; c < NI / 4; c++) {
        #pragma unroll
        for (int q = 0; q < 4; q++) {
            int ni = c * 4 + q;
            float bb = 0.f;
            if (BR) bb = bias[ni * 16 + m_lane];
            #pragma unroll
            for (int reg = 0; reg < 4; reg++) {
                float v = acc[ni][reg];
                if (BR) v = fmaxf(v + bb, 0.f);
                tr[wv * 1088 + (kgrp * 4 + reg) * 68 + q * 16 + m_lane] = v;
            }
        }
        // same-wave LDS RAW: in-order DS pipe + compiler lgkmcnt; no barrier needed
        #pragma unroll
        for (int j = 0; j < 4; j++) {
            int r = (lane >> 4) + j * 4;
            int g = lane & 15;
            float4 v = *(const float4*)&tr[wv * 1088 + r * 68 + g * 4];
            int row = brow + wv * 16 + r;
            if (row < M)
                *(float4*)&C[(size_t)row * BN + c * 64 + g * 4] = v;
        }
    }
}

// ---------------- aggregation: out[v] = sum_in h[u]*dis[u]*dis[v] + h[v]*dis[v]^2 (+ b, relu) ----
// R6 version (best measured): one wave per node, lane holds VPT floats; 8-edge batch ILP.

template<int F, bool RELU, bool BIAS>
__global__ void aggregate_kernel(const float* __restrict__ xw,
                                 float* __restrict__ out,
                                 const float* __restrict__ dis,
                                 const int* __restrict__ starts,
                                 const int* __restrict__ ends,
                                 const int* __restrict__ csr_src,
                                 const float* __restrict__ bias,
                                 int n) {
    int wave = (blockIdx.x * blockDim.x + threadIdx.x) >> 6;
    int lane = threadIdx.x & 63;
    if (wave >= n) return;
    int v = wave;
    constexpr int VPT = F / 64;
    float dv = dis[v];
    float acc[VPT];
    {
        const float* r = &xw[(size_t)v * F + lane * VPT];
        #pragma unroll
        for (int i = 0; i < VPT; i++) acc[i] = r[i] * dv * dv;
    }
    int s = starts[v], e = ends[v];
    int p = s;
    for (; p + 8 <= e; p += 8) {
        int u[8];
        #pragma unroll
        for (int q = 0; q < 8; q++) u[q] = csr_src[p + q];
        float w[8];
        #pragma unroll
        for (int q = 0; q < 8; q++) w[q] = dis[u[q]] * dv;
        if constexpr (VPT == 2) {
            float2 g[8];
            #pragma unroll
            for (int q = 0; q < 8; q++)
                g[q] = *(const float2*)&xw[(size_t)u[q] * F + lane * 2];
            #pragma unroll
            for (int q = 0; q < 8; q++) {
                acc[0] += g[q].x * w[q];
                acc[1] += g[q].y * w[q];
            }
        } else {
            float g[8];
            #pragma unroll
            for (int q = 0; q < 8; q++)
                g[q] = xw[(size_t)u[q] * F + lane];
            #pragma unroll
            for (int q = 0; q < 8; q++) acc[0] += g[q] * w[q];
        }
    }
    for (; p < e; p++) {
        int u = csr_src[p];
        float w = dis[u] * dv;
        const float* r = &xw[(size_t)u * F + lane * VPT];
        #pragma unroll
        for (int i = 0; i < VPT; i++) acc[i] += r[i] * w;
    }
    {
        float* o = &out[(size_t)v * F + lane * VPT];
        #pragma unroll
        for (int i = 0; i < VPT; i++) {
            float r = acc[i];
            if (BIAS) r += bias[lane * VPT + i];
            if (RELU) r = fmaxf(r, 0.f);
            o[i] = r;
        }
    }
}

// ---------------- edge dot products: out[e] = h[i0] . h[i1], F=64 ----------------

__global__ void dot_kernel(const float* __restrict__ h,
                           const int* __restrict__ pos, const int* __restrict__ neg,
                           float* __restrict__ out) {
    int t = blockIdx.x * blockDim.x + threadIdx.x;
    if (t >= E_POS + E_NEG) return;
    int i0, i1;
    if (t < E_POS) { i0 = pos[t]; i1 = pos[E_POS + t]; }
    else { int e = t - E_POS; i0 = neg[e]; i1 = neg[E_NEG + e]; }
    const float4* a = (const float4*)&h[(size_t)i0 * 64];
    const float4* b = (const float4*)&h[(size_t)i1 * 64];
    float s0 = 0.f, s1 = 0.f, s2 = 0.f, s3 = 0.f;
    #pragma unroll
    for (int k = 0; k < 16; k += 4) {
        float4 a0 = a[k + 0], a1 = a[k + 1], a2 = a[k + 2], a3 = a[k + 3];
        float4 b0 = b[k + 0], b1 = b[k + 1], b2 = b[k + 2], b3 = b[k + 3];
        s0 += a0.x * b0.x + a0.y * b0.y + a0.z * b0.z + a0.w * b0.w;
        s1 += a1.x * b1.x + a1.y * b1.y + a1.z * b1.z + a1.w * b1.w;
        s2 += a2.x * b2.x + a2.y * b2.y + a2.z * b2.z + a2.w * b2.w;
        s3 += a3.x * b3.x + a3.y * b3.y + a3.z * b3.z + a3.w * b3.w;
    }
    out[t] = (s0 + s1) + (s2 + s3);
}

// ---------------- launch ----------------

extern "C" void kernel_launch(void* const* d_in, const int* in_sizes, int n_in,
                              void* d_out, int out_size, void* d_ws, size_t ws_size,
                              hipStream_t stream) {
    const float* x  = (const float*)d_in[0];
    const int* tei  = (const int*)d_in[1];
    const int* pos  = (const int*)d_in[2];
    const int* neg  = (const int*)d_in[3];
    const float* W1 = (const float*)d_in[4];
    const float* b1 = (const float*)d_in[5];
    const float* W2 = (const float*)d_in[6];
    const float* b2 = (const float*)d_in[7];
    const float* W3 = (const float*)d_in[8];
    const float* b3 = (const float*)d_in[9];
    float* out = (float*)d_out;

    const int* src = tei;
    const int* dst = tei + E_TRAIN;

    char* ws = (char*)d_ws;
    size_t off = 0;
    auto alloc = [&](size_t bytes) -> void* {
        void* p = ws + off;
        off = (off + bytes + 255) & ~(size_t)255;
        return p;
    };
    float* bufA = (float*)alloc((size_t)N_NODES * 128 * 4);  // aggX / xw2 / xw3
    float* bufB = (float*)alloc((size_t)N_NODES * 256 * 4);  // h1, later h3
    float* bufC = (float*)alloc((size_t)N_NODES * 128 * 4);  // h2
    float* dis  = (float*)alloc(N_NODES * 4);
    int* cnt    = (int*)alloc(N_NODES * 4);
    int* offs   = (int*)alloc(N_NODES * 4);
    int* cursor = (int*)alloc(N_NODES * 4);
    int* bsum   = (int*)alloc(256 * 4);
    int* csr    = (int*)alloc((size_t)E_TRAIN * 4);
    short* Wt1h = (short*)alloc((size_t)128 * 256 * 2);
    short* Wt1l = (short*)alloc((size_t)128 * 256 * 2);
    short* Wt2h = (short*)alloc((size_t)256 * 128 * 2);
    short* Wt2l = (short*)alloc((size_t)256 * 128 * 2);
    short* Wt3h = (short*)alloc((size_t)128 * 64 * 2);
    short* Wt3l = (short*)alloc((size_t)128 * 64 * 2);
    (void)ws_size; (void)n_in; (void)in_sizes; (void)out_size;

    hipMemsetAsync(cnt, 0, N_NODES * 4, stream);
    count_kernel<<<(E_TRAIN + 255) / 256, 256, 0, stream>>>(dst, cnt, E_TRAIN);
    int nb = (N_NODES + 255) / 256;  // 196
    scan1_kernel<<<nb, 256, 0, stream>>>(cnt, offs, bsum, dis, N_NODES);
    scan2_kernel<<<1, 256, 0, stream>>>(bsum, nb);
    scan3_kernel<<<nb, 256, 0, stream>>>(offs, bsum, cursor, N_NODES);
    fill_kernel<<<(E_TRAIN + 255) / 256, 256, 0, stream>>>(src, dst, cursor, csr, E_TRAIN);
    // after fill: offs[v] = start, cursor[v] = end

    const int WTOT = 128 * 256 + 256 * 128 + 128 * 64;
    wsplit_all_kernel<<<(WTOT + 255) / 256, 256, 0, stream>>>(
        W1, Wt1h, Wt1l, W2, Wt2h, Wt2l, W3, Wt3h, Wt3l);

    const int GB = (N_NODES + 127) / 128;     // 391 blocks of 128 rows
    const int AGG_BLOCKS = (N_NODES + 3) / 4; // 4 waves/block, 1 node/wave

    // layer 1 (agg-first): aggX = agg(x) [F=128]; h1 = relu(aggX @ W1 + b1) [256]
    aggregate_kernel<128, false, false><<<AGG_BLOCKS, 256, 0, stream>>>(
        x, bufA, dis, offs, cursor, csr, nullptr, N_NODES);
    gemm_fulln_kernel<256, true><<<GB, 512, 0, stream>>>(
        bufA, Wt1h, Wt1l, b1, bufB, N_NODES, 128);

    // layer 2 (gemm-first): xw2 = h1 @ W2 [128]; h2 = relu(agg(xw2) + b2)
    gemm_fulln_kernel<128, false><<<GB, 512, 0, stream>>>(
        bufB, Wt2h, Wt2l, nullptr, bufA, N_NODES, 256);
    aggregate_kernel<128, true, true><<<AGG_BLOCKS, 256, 0, stream>>>(
        bufA, bufC, dis, offs, cursor, csr, b2, N_NODES);

    // layer 3 (gemm-first): xw3 = h2 @ W3 [64]; h3 = agg(xw3) + b3
    gemm_fulln_kernel<64, false><<<GB, 512, 0, stream>>>(
        bufC, Wt3h, Wt3l, nullptr, bufA, N_NODES, 128);
    aggregate_kernel<64, false, true><<<AGG_BLOCKS, 256, 0, stream>>>(
        bufA, bufB, dis, offs, cursor, csr, b3, N_NODES);

    // edge dots over h3 (64 features)
    dot_kernel<<<(E_POS + E_NEG + 255) / 256, 256, 0, stream>>>(bufB, pos, neg, out);
}

// Round 12
// 400.626 us; speedup vs baseline: 1.3266x; 1.1099x over previous
//
#include <hip/hip_runtime.h>
#include <math.h>

#define N_NODES 50000
#define E_TRAIN 800000
#define E_POS 200000
#define E_NEG 200000

// ---------------- degree / CSR build ----------------

__global__ void count_kernel(const int* __restrict__ dst, int* __restrict__ cnt, int e) {
    int i = blockIdx.x * blockDim.x + threadIdx.x;
    if (i < e) atomicAdd(&cnt[dst[i]], 1);
}

// scan1 + dis fused: block-level exclusive scan of cnt, plus dis = rsqrt(deg+1)
__global__ void scan1_kernel(const int* __restrict__ cnt, int* __restrict__ offs,
                             int* __restrict__ bsum, float* __restrict__ dis, int n) {
    __shared__ int s[256];
    int i = blockIdx.x * 256 + threadIdx.x;
    int c = (i < n) ? cnt[i] : 0;
    if (i < n) dis[i] = 1.0f / sqrtf((float)(c + 1));  // +1 self loop
    s[threadIdx.x] = c;
    __syncthreads();
    for (int d = 1; d < 256; d <<= 1) {
        int t = 0;
        if ((int)threadIdx.x >= d) t = s[threadIdx.x - d];
        __syncthreads();
        if ((int)threadIdx.x >= d) s[threadIdx.x] += t;
        __syncthreads();
    }
    if (i < n) offs[i] = s[threadIdx.x] - c;  // exclusive
    if (threadIdx.x == 255) bsum[blockIdx.x] = s[255];
}

__global__ void scan2_kernel(int* __restrict__ bsum, int nb) {
    __shared__ int s[256];
    int t = threadIdx.x;
    int v = (t < nb) ? bsum[t] : 0;
    s[t] = v;
    __syncthreads();
    for (int d = 1; d < 256; d <<= 1) {
        int u = 0;
        if (t >= d) u = s[t - d];
        __syncthreads();
        if (t >= d) s[t] += u;
        __syncthreads();
    }
    if (t < nb) bsum[t] = s[t] - v;  // exclusive
}

__global__ void scan3_kernel(int* __restrict__ offs, const int* __restrict__ bsum,
                             int* __restrict__ cursor, int n) {
    int i = blockIdx.x * 256 + threadIdx.x;   // blockDim must be 256
    if (i < n) { int o = offs[i] + bsum[i >> 8]; offs[i] = o; cursor[i] = o; }
}

__global__ void fill_kernel(const int* __restrict__ src, const int* __restrict__ dst,
                            int* __restrict__ cursor, int* __restrict__ csr_src, int e) {
    int i = blockIdx.x * blockDim.x + threadIdx.x;
    if (i < e) {
        int p = atomicAdd(&cursor[dst[i]], 1);
        csr_src[p] = src[i];
    }
}

// ---------------- bf16 helpers ----------------

__device__ inline void split_bf16(float f, short& h, short& l) {
    unsigned u = __float_as_uint(f);
    h = (short)(u >> 16);
    float rem = f - __uint_as_float(u & 0xFFFF0000u);
    l = (short)(__float_as_uint(rem) >> 16);
}

__device__ inline unsigned short f2bf_rne(float f) {
    unsigned u = __float_as_uint(f);
    unsigned r = u + 0x7FFFu + ((u >> 16) & 1u);
    return (unsigned short)(r >> 16);
}

__device__ inline float bf2f(unsigned short h) {
    return __uint_as_float(((unsigned)h) << 16);
}

// all three weights -> transposed hi/lo bf16 in one launch
__global__ void wsplit_all_kernel(const float* __restrict__ W1, short* __restrict__ W1h, short* __restrict__ W1l,
                                  const float* __restrict__ W2, short* __restrict__ W2h, short* __restrict__ W2l,
                                  const float* __restrict__ W3, short* __restrict__ W3h, short* __restrict__ W3l) {
    int i = blockIdx.x * blockDim.x + threadIdx.x;
    const float* W; short *Wh, *Wl; int K, N;
    if (i < 128 * 256) { W = W1; Wh = W1h; Wl = W1l; K = 128; N = 256; }
    else if (i < 128 * 256 + 256 * 128) { i -= 128 * 256; W = W2; Wh = W2h; Wl = W2l; K = 256; N = 128; }
    else if (i < 128 * 256 + 256 * 128 + 128 * 64) { i -= 128 * 256 + 256 * 128; W = W3; Wh = W3h; Wl = W3l; K = 128; N = 64; }
    else return;
    int k = i / N, n = i - k * N;
    short h, l;
    split_bf16(W[i], h, l);
    Wh[(size_t)n * K + k] = h;
    Wl[(size_t)n * K + k] = l;
}

// x (fp32) -> bf16 RNE gather table
__global__ void xconv_kernel(const float* __restrict__ x, unsigned short* __restrict__ xb, int n4) {
    int i = blockIdx.x * blockDim.x + threadIdx.x;
    if (i < n4) {
        float4 v = ((const float4*)x)[i];
        ushort4 o;
        o.x = f2bf_rne(v.x); o.y = f2bf_rne(v.y);
        o.z = f2bf_rne(v.z); o.w = f2bf_rne(v.w);
        ((ushort4*)xb)[i] = o;
    }
}

// ---------------- MFMA GEMM: 512 threads, 128 rows x full N, A streamed, B in LDS ----------------
// (R11 structure, proven: 8 waves/block, register-prefetch, transpose epilogue.)
// OBF: emit C as bf16 RNE (ushort) for gather consumers; else fp32.

typedef short bf16x8 __attribute__((ext_vector_type(8)));
typedef float f32x4 __attribute__((ext_vector_type(4)));

template<int BN, bool BR, bool OBF>
__global__ __launch_bounds__(512) void gemm_fulln_kernel(
        const float* __restrict__ A,
        const short* __restrict__ Bth, const short* __restrict__ Btl,
        const float* __restrict__ bias, float* __restrict__ C,
        unsigned short* __restrict__ Cb,
        int M, int K) {
    constexpr int NI = BN / 16;              // 16x16 tiles per wave
    constexpr int BCH = BN * 4;              // int4 chunks per B array per k-tile
    constexpr int BP = (BCH + 511) / 512;    // chunks per thread
    constexpr size_t BSZ = (size_t)2 * BN * 40 * 2;   // hi+lo, stride 40 shorts
    constexpr size_t TSZ = (size_t)8 * 16 * 68 * 4;   // 8-wave transpose buffer
    __shared__ __align__(16) char smem[BSZ > TSZ ? BSZ : TSZ];
    short* Bhi = (short*)smem;
    short* Blo = (short*)(smem + (size_t)BN * 40 * 2);
    float* tr  = (float*)smem;               // aliased after final barrier

    int tid = threadIdx.x;
    int lane = tid & 63;
    int wv = tid >> 6;                       // 0..7
    int brow = blockIdx.x * 128;
    int m_lane = lane & 15;
    int kgrp = lane >> 4;                    // 0..3

    int myrow = brow + wv * 16 + m_lane;
    if (myrow >= M) myrow = M - 1;           // clamp; garbage rows discarded at store
    const float* Ap = &A[(size_t)myrow * K + kgrp * 8];

    f32x4 acc[NI];
    #pragma unroll
    for (int i = 0; i < NI; i++) acc[i] = (f32x4){0.f, 0.f, 0.f, 0.f};

    int4 bhReg[BP], blReg[BP];
    float4 aN0, aN1, aC0, aC1;

    auto loadB = [&](int k0) {
        #pragma unroll
        for (int p = 0; p < BP; p++) {
            int idx = p * 512 + tid;
            if (idx < BCH) {
                int col = idx >> 2;
                int kc = idx & 3;
                size_t o = (size_t)col * K + k0 + kc * 8;
                bhReg[p] = *(const int4*)&Bth[o];
                blReg[p] = *(const int4*)&Btl[o];
            }
        }
    };
    auto loadA = [&](int k0) {
        aN0 = *(const float4*)&Ap[k0];
        aN1 = *(const float4*)&Ap[k0 + 4];
    };

    loadB(0); loadA(0);

    for (int k0 = 0; k0 < K; k0 += 32) {
        aC0 = aN0; aC1 = aN1;
        #pragma unroll
        for (int p = 0; p < BP; p++) {
            int idx = p * 512 + tid;
            if (idx < BCH) {
                int col = idx >> 2;
                int kc = idx & 3;
                *(int4*)&Bhi[col * 40 + kc * 8] = bhReg[p];
                *(int4*)&Blo[col * 40 + kc * 8] = blReg[p];
            }
        }
        __syncthreads();

        if (k0 + 32 < K) { loadB(k0 + 32); loadA(k0 + 32); }  // overlaps MFMA phase

        bf16x8 ah, al;
        {
            short h, l;
            split_bf16(aC0.x, h, l); ah[0] = h; al[0] = l;
            split_bf16(aC0.y, h, l); ah[1] = h; al[1] = l;
            split_bf16(aC0.z, h, l); ah[2] = h; al[2] = l;
            split_bf16(aC0.w, h, l); ah[3] = h; al[3] = l;
            split_bf16(aC1.x, h, l); ah[4] = h; al[4] = l;
            split_bf16(aC1.y, h, l); ah[5] = h; al[5] = l;
            split_bf16(aC1.z, h, l); ah[6] = h; al[6] = l;
            split_bf16(aC1.w, h, l); ah[7] = h; al[7] = l;
        }
        #pragma unroll
        for (int ni = 0; ni < NI; ni++) {
            int boff = (ni * 16 + m_lane) * 40 + kgrp * 8;
            bf16x8 bh = *(const bf16x8*)&Bhi[boff];
            bf16x8 bl = *(const bf16x8*)&Blo[boff];
            acc[ni] = __builtin_amdgcn_mfma_f32_16x16x32_bf16(ah, bh, acc[ni], 0, 0, 0);
            acc[ni] = __builtin_amdgcn_mfma_f32_16x16x32_bf16(al, bh, acc[ni], 0, 0, 0);
            acc[ni] = __builtin_amdgcn_mfma_f32_16x16x32_bf16(ah, bl, acc[ni], 0, 0, 0);
        }
        __syncthreads();
    }

    // epilogue: acc col = ni*16 + m_lane, local row = kgrp*4 + reg.
    // Chunks of 4 ni (64 cols): wave-local LDS transpose, then coalesced stores.
    #pragma unroll
    for (int c = 0; c < NI / 4; c++) {
        #pragma unroll
        for (int q = 0; q < 4; q++) {
            int ni = c * 4 + q;
            float bb = 0.f;
            if (BR) bb = bias[ni * 16 + m_lane];
            #pragma unroll
            for (int reg = 0; reg < 4; reg++) {
                float v = acc[ni][reg];
                if (BR) v = fmaxf(v + bb, 0.f);
                tr[wv * 1088 + (kgrp * 4 + reg) * 68 + q * 16 + m_lane] = v;
            }
        }
        // same-wave LDS RAW: in-order DS pipe + compiler lgkmcnt; no barrier needed
        #pragma unroll
        for (int j = 0; j < 4; j++) {
            int r = (lane >> 4) + j * 4;
            int g = lane & 15;
            float4 v = *(const float4*)&tr[wv * 1088 + r * 68 + g * 4];
            int row = brow + wv * 16 + r;
            if (row < M) {
                if (OBF) {
                    ushort4 o;
                    o.x = f2bf_rne(v.x); o.y = f2bf_rne(v.y);
                    o.z = f2bf_rne(v.z); o.w = f2bf_rne(v.w);
                    *(ushort4*)&Cb[(size_t)row * BN + c * 64 + g * 4] = o;
                } else {
                    *(float4*)&C[(size_t)row * BN + c * 64 + g * 4] = v;
                }
            }
        }
    }
}

// ---------------- aggregation over bf16 gather table ----------------
// out[v] = sum_in xb[u]*dis[u]*dis[v] + xb[v]*dis[v]^2 (+ b, relu), fp32 accumulate/output.
// R6 ILP structure (best measured): one wave per node, 8-edge batches.
// F=128: lane gathers ushort2 (4B); F=64: lane gathers ushort (2B).

template<int F, bool RELU, bool BIAS>
__global__ void aggregate_bf16_kernel(const unsigned short* __restrict__ xb,
                                      float* __restrict__ out,
                                      const float* __restrict__ dis,
                                      const int* __restrict__ starts,
                                      const int* __restrict__ ends,
                                      const int* __restrict__ csr_src,
                                      const float* __restrict__ bias,
                                      int n) {
    int wave = (blockIdx.x * blockDim.x + threadIdx.x) >> 6;
    int lane = threadIdx.x & 63;
    if (wave >= n) return;
    int v = wave;
    constexpr int VPT = F / 64;
    float dv = dis[v];
    float acc[VPT];
    if constexpr (VPT == 2) {
        ushort2 sv = *(const ushort2*)&xb[(size_t)v * F + lane * 2];
        acc[0] = bf2f(sv.x) * dv * dv;
        acc[1] = bf2f(sv.y) * dv * dv;
    } else {
        acc[0] = bf2f(xb[(size_t)v * F + lane]) * dv * dv;
    }
    int s = starts[v], e = ends[v];
    int p = s;
    for (; p + 8 <= e; p += 8) {
        int u[8];
        #pragma unroll
        for (int q = 0; q < 8; q++) u[q] = csr_src[p + q];
        float w[8];
        #pragma unroll
        for (int q = 0; q < 8; q++) w[q] = dis[u[q]] * dv;
        if constexpr (VPT == 2) {
            ushort2 g[8];
            #pragma unroll
            for (int q = 0; q < 8; q++)
                g[q] = *(const ushort2*)&xb[(size_t)u[q] * F + lane * 2];
            #pragma unroll
            for (int q = 0; q < 8; q++) {
                acc[0] += bf2f(g[q].x) * w[q];
                acc[1] += bf2f(g[q].y) * w[q];
            }
        } else {
            unsigned short g[8];
            #pragma unroll
            for (int q = 0; q < 8; q++)
                g[q] = xb[(size_t)u[q] * F + lane];
            #pragma unroll
            for (int q = 0; q < 8; q++) acc[0] += bf2f(g[q]) * w[q];
        }
    }
    for (; p < e; p++) {
        int u = csr_src[p];
        float w = dis[u] * dv;
        if constexpr (VPT == 2) {
            ushort2 g = *(const ushort2*)&xb[(size_t)u * F + lane * 2];
            acc[0] += bf2f(g.x) * w;
            acc[1] += bf2f(g.y) * w;
        } else {
            acc[0] += bf2f(xb[(size_t)u * F + lane]) * w;
        }
    }
    {
        float* o = &out[(size_t)v * F + lane * VPT];
        #pragma unroll
        for (int i = 0; i < VPT; i++) {
            float r = acc[i];
            if (BIAS) r += bias[lane * VPT + i];
            if (RELU) r = fmaxf(r, 0.f);
            o[i] = r;
        }
    }
}

// ---------------- edge dot products: out[e] = h[i0] . h[i1], F=64 (fp32) ----------------

__global__ void dot_kernel(const float* __restrict__ h,
                           const int* __restrict__ pos, const int* __restrict__ neg,
                           float* __restrict__ out) {
    int t = blockIdx.x * blockDim.x + threadIdx.x;
    if (t >= E_POS + E_NEG) return;
    int i0, i1;
    if (t < E_POS) { i0 = pos[t]; i1 = pos[E_POS + t]; }
    else { int e = t - E_POS; i0 = neg[e]; i1 = neg[E_NEG + e]; }
    const float4* a = (const float4*)&h[(size_t)i0 * 64];
    const float4* b = (const float4*)&h[(size_t)i1 * 64];
    float s0 = 0.f, s1 = 0.f, s2 = 0.f, s3 = 0.f;
    #pragma unroll
    for (int k = 0; k < 16; k += 4) {
        float4 a0 = a[k + 0], a1 = a[k + 1], a2 = a[k + 2], a3 = a[k + 3];
        float4 b0 = b[k + 0], b1 = b[k + 1], b2 = b[k + 2], b3 = b[k + 3];
        s0 += a0.x * b0.x + a0.y * b0.y + a0.z * b0.z + a0.w * b0.w;
        s1 += a1.x * b1.x + a1.y * b1.y + a1.z * b1.z + a1.w * b1.w;
        s2 += a2.x * b2.x + a2.y * b2.y + a2.z * b2.z + a2.w * b2.w;
        s3 += a3.x * b3.x + a3.y * b3.y + a3.z * b3.z + a3.w * b3.w;
    }
    out[t] = (s0 + s1) + (s2 + s3);
}

// ---------------- launch ----------------

extern "C" void kernel_launch(void* const* d_in, const int* in_sizes, int n_in,
                              void* d_out, int out_size, void* d_ws, size_t ws_size,
                              hipStream_t stream) {
    const float* x  = (const float*)d_in[0];
    const int* tei  = (const int*)d_in[1];
    const int* pos  = (const int*)d_in[2];
    const int* neg  = (const int*)d_in[3];
    const float* W1 = (const float*)d_in[4];
    const float* b1 = (const float*)d_in[5];
    const float* W2 = (const float*)d_in[6];
    const float* b2 = (const float*)d_in[7];
    const float* W3 = (const float*)d_in[8];
    const float* b3 = (const float*)d_in[9];
    float* out = (float*)d_out;

    const int* src = tei;
    const int* dst = tei + E_TRAIN;

    char* ws = (char*)d_ws;
    size_t off = 0;
    auto alloc = [&](size_t bytes) -> void* {
        void* p = ws + off;
        off = (off + bytes + 255) & ~(size_t)255;
        return p;
    };
    unsigned short* xb   = (unsigned short*)alloc((size_t)N_NODES * 128 * 2);  // x bf16
    float* aggX          = (float*)alloc((size_t)N_NODES * 128 * 4);
    float* h1            = (float*)alloc((size_t)N_NODES * 256 * 4);
    unsigned short* xw2b = (unsigned short*)alloc((size_t)N_NODES * 128 * 2);
    float* h2            = (float*)alloc((size_t)N_NODES * 128 * 4);
    unsigned short* xw3b = (unsigned short*)alloc((size_t)N_NODES * 64 * 2);
    float* h3            = (float*)alloc((size_t)N_NODES * 64 * 4);
    float* dis  = (float*)alloc(N_NODES * 4);
    int* cnt    = (int*)alloc(N_NODES * 4);
    int* offs   = (int*)alloc(N_NODES * 4);
    int* cursor = (int*)alloc(N_NODES * 4);
    int* bsum   = (int*)alloc(256 * 4);
    int* csr    = (int*)alloc((size_t)E_TRAIN * 4);
    short* Wt1h = (short*)alloc((size_t)128 * 256 * 2);
    short* Wt1l = (short*)alloc((size_t)128 * 256 * 2);
    short* Wt2h = (short*)alloc((size_t)256 * 128 * 2);
    short* Wt2l = (short*)alloc((size_t)256 * 128 * 2);
    short* Wt3h = (short*)alloc((size_t)128 * 64 * 2);
    short* Wt3l = (short*)alloc((size_t)128 * 64 * 2);
    (void)ws_size; (void)n_in; (void)in_sizes; (void)out_size;

    hipMemsetAsync(cnt, 0, N_NODES * 4, stream);
    count_kernel<<<(E_TRAIN + 255) / 256, 256, 0, stream>>>(dst, cnt, E_TRAIN);
    int nb = (N_NODES + 255) / 256;  // 196
    scan1_kernel<<<nb, 256, 0, stream>>>(cnt, offs, bsum, dis, N_NODES);
    scan2_kernel<<<1, 256, 0, stream>>>(bsum, nb);
    scan3_kernel<<<nb, 256, 0, stream>>>(offs, bsum, cursor, N_NODES);
    fill_kernel<<<(E_TRAIN + 255) / 256, 256, 0, stream>>>(src, dst, cursor, csr, E_TRAIN);
    // after fill: offs[v] = start, cursor[v] = end

    const int WTOT = 128 * 256 + 256 * 128 + 128 * 64;
    wsplit_all_kernel<<<(WTOT + 255) / 256, 256, 0, stream>>>(
        W1, Wt1h, Wt1l, W2, Wt2h, Wt2l, W3, Wt3h, Wt3l);
    xconv_kernel<<<(N_NODES * 128 / 4 + 255) / 256, 256, 0, stream>>>(
        x, xb, N_NODES * 128 / 4);

    const int GB = (N_NODES + 127) / 128;     // 391 blocks of 128 rows
    const int AGG_BLOCKS = (N_NODES + 3) / 4; // 4 waves/block, 1 node/wave

    // layer 1 (agg-first): aggX = agg(xb) [F=128, fp32 out]; h1 = relu(aggX @ W1 + b1) [256 fp32]
    aggregate_bf16_kernel<128, false, false><<<AGG_BLOCKS, 256, 0, stream>>>(
        xb, aggX, dis, offs, cursor, csr, nullptr, N_NODES);
    gemm_fulln_kernel<256, true, false><<<GB, 512, 0, stream>>>(
        aggX, Wt1h, Wt1l, b1, h1, nullptr, N_NODES, 128);

    // layer 2 (gemm-first): xw2 = h1 @ W2 [128, bf16 out]; h2 = relu(agg(xw2b) + b2) [fp32]
    gemm_fulln_kernel<128, false, true><<<GB, 512, 0, stream>>>(
        h1, Wt2h, Wt2l, nullptr, nullptr, xw2b, N_NODES, 256);
    aggregate_bf16_kernel<128, true, true><<<AGG_BLOCKS, 256, 0, stream>>>(
        xw2b, h2, dis, offs, cursor, csr, b2, N_NODES);

    // layer 3 (gemm-first): xw3 = h2 @ W3 [64, bf16 out]; h3 = agg(xw3b) + b3 [fp32]
    gemm_fulln_kernel<64, false, true><<<GB, 512, 0, stream>>>(
        h2, Wt3h, Wt3l, nullptr, nullptr, xw3b, N_NODES, 128);
    aggregate_bf16_kernel<64, false, true><<<AGG_BLOCKS, 256, 0, stream>>>(
        xw3b, h3, dis, offs, cursor, csr, b3, N_NODES);

    // edge dots over h3 (64 features, fp32)
    dot_kernel<<<(E_POS + E_NEG + 255) / 256, 256, 0, stream>>>(h3, pos, neg, out);
}

// Round 13
// 394.980 us; speedup vs baseline: 1.3456x; 1.0143x over previous
//
#include <hip/hip_runtime.h>
#include <math.h>

#define N_NODES 50000
#define E_TRAIN 800000
#define E_POS 200000
#define E_NEG 200000

// ---------------- degree / CSR build ----------------

__global__ void count_kernel(const int* __restrict__ dst, int* __restrict__ cnt, int e) {
    int i = blockIdx.x * blockDim.x + threadIdx.x;
    if (i < e) atomicAdd(&cnt[dst[i]], 1);
}

// scan1 + dis fused: block-level exclusive scan of cnt, plus dis = rsqrt(deg+1)
__global__ void scan1_kernel(const int* __restrict__ cnt, int* __restrict__ offs,
                             int* __restrict__ bsum, float* __restrict__ dis, int n) {
    __shared__ int s[256];
    int i = blockIdx.x * 256 + threadIdx.x;
    int c = (i < n) ? cnt[i] : 0;
    if (i < n) dis[i] = 1.0f / sqrtf((float)(c + 1));  // +1 self loop
    s[threadIdx.x] = c;
    __syncthreads();
    for (int d = 1; d < 256; d <<= 1) {
        int t = 0;
        if ((int)threadIdx.x >= d) t = s[threadIdx.x - d];
        __syncthreads();
        if ((int)threadIdx.x >= d) s[threadIdx.x] += t;
        __syncthreads();
    }
    if (i < n) offs[i] = s[threadIdx.x] - c;  // exclusive
    if (threadIdx.x == 255) bsum[blockIdx.x] = s[255];
}

__global__ void scan2_kernel(int* __restrict__ bsum, int nb) {
    __shared__ int s[256];
    int t = threadIdx.x;
    int v = (t < nb) ? bsum[t] : 0;
    s[t] = v;
    __syncthreads();
    for (int d = 1; d < 256; d <<= 1) {
        int u = 0;
        if (t >= d) u = s[t - d];
        __syncthreads();
        if (t >= d) s[t] += u;
        __syncthreads();
    }
    if (t < nb) bsum[t] = s[t] - v;  // exclusive
}

__global__ void scan3_kernel(int* __restrict__ offs, const int* __restrict__ bsum,
                             int* __restrict__ cursor, int n) {
    int i = blockIdx.x * 256 + threadIdx.x;   // blockDim must be 256
    if (i < n) { int o = offs[i] + bsum[i >> 8]; offs[i] = o; cursor[i] = o; }
}

// csr entries are ushort: src node ids < 50000 < 65536
__global__ void fill_kernel(const int* __restrict__ src, const int* __restrict__ dst,
                            int* __restrict__ cursor, unsigned short* __restrict__ csr_src, int e) {
    int i = blockIdx.x * blockDim.x + threadIdx.x;
    if (i < e) {
        int p = atomicAdd(&cursor[dst[i]], 1);
        csr_src[p] = (unsigned short)src[i];
    }
}

// ---------------- bf16 helpers ----------------

__device__ inline void split_bf16(float f, short& h, short& l) {
    unsigned u = __float_as_uint(f);
    h = (short)(u >> 16);
    float rem = f - __uint_as_float(u & 0xFFFF0000u);
    l = (short)(__float_as_uint(rem) >> 16);
}

__device__ inline unsigned short f2bf_rne(float f) {
    unsigned u = __float_as_uint(f);
    unsigned r = u + 0x7FFFu + ((u >> 16) & 1u);
    return (unsigned short)(r >> 16);
}

__device__ inline float bf2f(unsigned short h) {
    return __uint_as_float(((unsigned)h) << 16);
}

// all three weights -> transposed hi/lo bf16 in one launch
__global__ void wsplit_all_kernel(const float* __restrict__ W1, short* __restrict__ W1h, short* __restrict__ W1l,
                                  const float* __restrict__ W2, short* __restrict__ W2h, short* __restrict__ W2l,
                                  const float* __restrict__ W3, short* __restrict__ W3h, short* __restrict__ W3l) {
    int i = blockIdx.x * blockDim.x + threadIdx.x;
    const float* W; short *Wh, *Wl; int K, N;
    if (i < 128 * 256) { W = W1; Wh = W1h; Wl = W1l; K = 128; N = 256; }
    else if (i < 128 * 256 + 256 * 128) { i -= 128 * 256; W = W2; Wh = W2h; Wl = W2l; K = 256; N = 128; }
    else if (i < 128 * 256 + 256 * 128 + 128 * 64) { i -= 128 * 256 + 256 * 128; W = W3; Wh = W3h; Wl = W3l; K = 128; N = 64; }
    else return;
    int k = i / N, n = i - k * N;
    short h, l;
    split_bf16(W[i], h, l);
    Wh[(size_t)n * K + k] = h;
    Wl[(size_t)n * K + k] = l;
}

// x (fp32) -> bf16 RNE gather table
__global__ void xconv_kernel(const float* __restrict__ x, unsigned short* __restrict__ xb, int n4) {
    int i = blockIdx.x * blockDim.x + threadIdx.x;
    if (i < n4) {
        float4 v = ((const float4*)x)[i];
        ushort4 o;
        o.x = f2bf_rne(v.x); o.y = f2bf_rne(v.y);
        o.z = f2bf_rne(v.z); o.w = f2bf_rne(v.w);
        ((ushort4*)xb)[i] = o;
    }
}

// ---------------- MFMA GEMM: 512 threads, 128 rows x full N, A streamed, B in LDS ----------------
// (R11 structure, proven: 8 waves/block, register-prefetch, transpose epilogue.)
// OBF: emit C as bf16 RNE (ushort) for gather consumers; else fp32.

typedef short bf16x8 __attribute__((ext_vector_type(8)));
typedef float f32x4 __attribute__((ext_vector_type(4)));

template<int BN, bool BR, bool OBF>
__global__ __launch_bounds__(512) void gemm_fulln_kernel(
        const float* __restrict__ A,
        const short* __restrict__ Bth, const short* __restrict__ Btl,
        const float* __restrict__ bias, float* __restrict__ C,
        unsigned short* __restrict__ Cb,
        int M, int K) {
    constexpr int NI = BN / 16;              // 16x16 tiles per wave
    constexpr int BCH = BN * 4;              // int4 chunks per B array per k-tile
    constexpr int BP = (BCH + 511) / 512;    // chunks per thread
    constexpr size_t BSZ = (size_t)2 * BN * 40 * 2;   // hi+lo, stride 40 shorts
    constexpr size_t TSZ = (size_t)8 * 16 * 68 * 4;   // 8-wave transpose buffer
    __shared__ __align__(16) char smem[BSZ > TSZ ? BSZ : TSZ];
    short* Bhi = (short*)smem;
    short* Blo = (short*)(smem + (size_t)BN * 40 * 2);
    float* tr  = (float*)smem;               // aliased after final barrier

    int tid = threadIdx.x;
    int lane = tid & 63;
    int wv = tid >> 6;                       // 0..7
    int brow = blockIdx.x * 128;
    int m_lane = lane & 15;
    int kgrp = lane >> 4;                    // 0..3

    int myrow = brow + wv * 16 + m_lane;
    if (myrow >= M) myrow = M - 1;           // clamp; garbage rows discarded at store
    const float* Ap = &A[(size_t)myrow * K + kgrp * 8];

    f32x4 acc[NI];
    #pragma unroll
    for (int i = 0; i < NI; i++) acc[i] = (f32x4){0.f, 0.f, 0.f, 0.f};

    int4 bhReg[BP], blReg[BP];
    float4 aN0, aN1, aC0, aC1;

    auto loadB = [&](int k0) {
        #pragma unroll
        for (int p = 0; p < BP; p++) {
            int idx = p * 512 + tid;
            if (idx < BCH) {
                int col = idx >> 2;
                int kc = idx & 3;
                size_t o = (size_t)col * K + k0 + kc * 8;
                bhReg[p] = *(const int4*)&Bth[o];
                blReg[p] = *(const int4*)&Btl[o];
            }
        }
    };
    auto loadA = [&](int k0) {
        aN0 = *(const float4*)&Ap[k0];
        aN1 = *(const float4*)&Ap[k0 + 4];
    };

    loadB(0); loadA(0);

    for (int k0 = 0; k0 < K; k0 += 32) {
        aC0 = aN0; aC1 = aN1;
        #pragma unroll
        for (int p = 0; p < BP; p++) {
            int idx = p * 512 + tid;
            if (idx < BCH) {
                int col = idx >> 2;
                int kc = idx & 3;
                *(int4*)&Bhi[col * 40 + kc * 8] = bhReg[p];
                *(int4*)&Blo[col * 40 + kc * 8] = blReg[p];
            }
        }
        __syncthreads();

        if (k0 + 32 < K) { loadB(k0 + 32); loadA(k0 + 32); }  // overlaps MFMA phase

        bf16x8 ah, al;
        {
            short h, l;
            split_bf16(aC0.x, h, l); ah[0] = h; al[0] = l;
            split_bf16(aC0.y, h, l); ah[1] = h; al[1] = l;
            split_bf16(aC0.z, h, l); ah[2] = h; al[2] = l;
            split_bf16(aC0.w, h, l); ah[3] = h; al[3] = l;
            split_bf16(aC1.x, h, l); ah[4] = h; al[4] = l;
            split_bf16(aC1.y, h, l); ah[5] = h; al[5] = l;
            split_bf16(aC1.z, h, l); ah[6] = h; al[6] = l;
            split_bf16(aC1.w, h, l); ah[7] = h; al[7] = l;
        }
        #pragma unroll
        for (int ni = 0; ni < NI; ni++) {
            int boff = (ni * 16 + m_lane) * 40 + kgrp * 8;
            bf16x8 bh = *(const bf16x8*)&Bhi[boff];
            bf16x8 bl = *(const bf16x8*)&Blo[boff];
            acc[ni] = __builtin_amdgcn_mfma_f32_16x16x32_bf16(ah, bh, acc[ni], 0, 0, 0);
            acc[ni] = __builtin_amdgcn_mfma_f32_16x16x32_bf16(al, bh, acc[ni], 0, 0, 0);
            acc[ni] = __builtin_amdgcn_mfma_f32_16x16x32_bf16(ah, bl, acc[ni], 0, 0, 0);
        }
        __syncthreads();
    }

    // epilogue: acc col = ni*16 + m_lane, local row = kgrp*4 + reg.
    // Chunks of 4 ni (64 cols): wave-local LDS transpose, then coalesced stores.
    #pragma unroll
    for (int c = 0; c < NI / 4; c++) {
        #pragma unroll
        for (int q = 0; q < 4; q++) {
            int ni = c * 4 + q;
            float bb = 0.f;
            if (BR) bb = bias[ni * 16 + m_lane];
            #pragma unroll
            for (int reg = 0; reg < 4; reg++) {
                float v = acc[ni][reg];
                if (BR) v = fmaxf(v + bb, 0.f);
                tr[wv * 1088 + (kgrp * 4 + reg) * 68 + q * 16 + m_lane] = v;
            }
        }
        // same-wave LDS RAW: in-order DS pipe + compiler lgkmcnt; no barrier needed
        #pragma unroll
        for (int j = 0; j < 4; j++) {
            int r = (lane >> 4) + j * 4;
            int g = lane & 15;
            float4 v = *(const float4*)&tr[wv * 1088 + r * 68 + g * 4];
            int row = brow + wv * 16 + r;
            if (row < M) {
                if (OBF) {
                    ushort4 o;
                    o.x = f2bf_rne(v.x); o.y = f2bf_rne(v.y);
                    o.z = f2bf_rne(v.z); o.w = f2bf_rne(v.w);
                    *(ushort4*)&Cb[(size_t)row * BN + c * 64 + g * 4] = o;
                } else {
                    *(float4*)&C[(size_t)row * BN + c * 64 + g * 4] = v;
                }
            }
        }
    }
}

// ---------------- aggregation over bf16 gather table (ushort csr) ----------------
// out[v] = sum_in xb[u]*dis[u]*dis[v] + xb[v]*dis[v]^2 (+ b, relu), fp32 accumulate/output.

template<int F, bool RELU, bool BIAS>
__global__ void aggregate_bf16_kernel(const unsigned short* __restrict__ xb,
                                      float* __restrict__ out,
                                      const float* __restrict__ dis,
                                      const int* __restrict__ starts,
                                      const int* __restrict__ ends,
                                      const unsigned short* __restrict__ csr_src,
                                      const float* __restrict__ bias,
                                      int n) {
    int wave = (blockIdx.x * blockDim.x + threadIdx.x) >> 6;
    int lane = threadIdx.x & 63;
    if (wave >= n) return;
    int v = wave;
    constexpr int VPT = F / 64;
    float dv = dis[v];
    float acc[VPT];
    if constexpr (VPT == 2) {
        ushort2 sv = *(const ushort2*)&xb[(size_t)v * F + lane * 2];
        acc[0] = bf2f(sv.x) * dv * dv;
        acc[1] = bf2f(sv.y) * dv * dv;
    } else {
        acc[0] = bf2f(xb[(size_t)v * F + lane]) * dv * dv;
    }
    int s = starts[v], e = ends[v];
    int p = s;
    for (; p + 8 <= e; p += 8) {
        int u[8];
        #pragma unroll
        for (int q = 0; q < 8; q++) u[q] = csr_src[p + q];
        float w[8];
        #pragma unroll
        for (int q = 0; q < 8; q++) w[q] = dis[u[q]] * dv;
        if constexpr (VPT == 2) {
            ushort2 g[8];
            #pragma unroll
            for (int q = 0; q < 8; q++)
                g[q] = *(const ushort2*)&xb[(size_t)u[q] * F + lane * 2];
            #pragma unroll
            for (int q = 0; q < 8; q++) {
                acc[0] += bf2f(g[q].x) * w[q];
                acc[1] += bf2f(g[q].y) * w[q];
            }
        } else {
            unsigned short g[8];
            #pragma unroll
            for (int q = 0; q < 8; q++)
                g[q] = xb[(size_t)u[q] * F + lane];
            #pragma unroll
            for (int q = 0; q < 8; q++) acc[0] += bf2f(g[q]) * w[q];
        }
    }
    for (; p < e; p++) {
        int u = csr_src[p];
        float w = dis[u] * dv;
        if constexpr (VPT == 2) {
            ushort2 g = *(const ushort2*)&xb[(size_t)u * F + lane * 2];
            acc[0] += bf2f(g.x) * w;
            acc[1] += bf2f(g.y) * w;
        } else {
            acc[0] += bf2f(xb[(size_t)u * F + lane]) * w;
        }
    }
    {
        float* o = &out[(size_t)v * F + lane * VPT];
        #pragma unroll
        for (int i = 0; i < VPT; i++) {
            float r = acc[i];
            if (BIAS) r += bias[lane * VPT + i];
            if (RELU) r = fmaxf(r, 0.f);
            o[i] = r;
        }
    }
}

// ---------------- edge dot products: 16 lanes per edge, 4 edges per wave ----------------
// Lane pl in [0,16) loads float4 pl of each row -> per instruction a wave gathers
// 4 x 256B contiguous rows. 4-step shfl_xor reduce within 16-lane groups.

__global__ void dot_kernel(const float* __restrict__ h,
                           const int* __restrict__ pos, const int* __restrict__ neg,
                           float* __restrict__ out) {
    int gw = (blockIdx.x * blockDim.x + threadIdx.x) >> 6;
    int lane = threadIdx.x & 63;
    int sub = lane >> 4;          // edge within wave (0..3)
    int pl = lane & 15;           // float4 position within row
    int e = gw * 4 + sub;
    if (e >= E_POS + E_NEG) return;
    int i0, i1;
    if (e < E_POS) { i0 = pos[e]; i1 = pos[E_POS + e]; }
    else { int t = e - E_POS; i0 = neg[t]; i1 = neg[E_NEG + t]; }
    float4 a = *(const float4*)&h[(size_t)i0 * 64 + pl * 4];
    float4 b = *(const float4*)&h[(size_t)i1 * 64 + pl * 4];
    float v = a.x * b.x + a.y * b.y + a.z * b.z + a.w * b.w;
    v += __shfl_xor(v, 1, 64);
    v += __shfl_xor(v, 2, 64);
    v += __shfl_xor(v, 4, 64);
    v += __shfl_xor(v, 8, 64);
    if (pl == 0) out[e] = v;
}

// ---------------- launch ----------------

extern "C" void kernel_launch(void* const* d_in, const int* in_sizes, int n_in,
                              void* d_out, int out_size, void* d_ws, size_t ws_size,
                              hipStream_t stream) {
    const float* x  = (const float*)d_in[0];
    const int* tei  = (const int*)d_in[1];
    const int* pos  = (const int*)d_in[2];
    const int* neg  = (const int*)d_in[3];
    const float* W1 = (const float*)d_in[4];
    const float* b1 = (const float*)d_in[5];
    const float* W2 = (const float*)d_in[6];
    const float* b2 = (const float*)d_in[7];
    const float* W3 = (const float*)d_in[8];
    const float* b3 = (const float*)d_in[9];
    float* out = (float*)d_out;

    const int* src = tei;
    const int* dst = tei + E_TRAIN;

    char* ws = (char*)d_ws;
    size_t off = 0;
    auto alloc = [&](size_t bytes) -> void* {
        void* p = ws + off;
        off = (off + bytes + 255) & ~(size_t)255;
        return p;
    };
    unsigned short* xb   = (unsigned short*)alloc((size_t)N_NODES * 128 * 2);  // x bf16
    float* aggX          = (float*)alloc((size_t)N_NODES * 128 * 4);
    float* h1            = (float*)alloc((size_t)N_NODES * 256 * 4);
    unsigned short* xw2b = (unsigned short*)alloc((size_t)N_NODES * 128 * 2);
    float* h2            = (float*)alloc((size_t)N_NODES * 128 * 4);
    unsigned short* xw3b = (unsigned short*)alloc((size_t)N_NODES * 64 * 2);
    float* h3            = (float*)alloc((size_t)N_NODES * 64 * 4);
    float* dis  = (float*)alloc(N_NODES * 4);
    int* cnt    = (int*)alloc(N_NODES * 4);
    int* offs   = (int*)alloc(N_NODES * 4);
    int* cursor = (int*)alloc(N_NODES * 4);
    int* bsum   = (int*)alloc(256 * 4);
    unsigned short* csr = (unsigned short*)alloc((size_t)E_TRAIN * 2);
    short* Wt1h = (short*)alloc((size_t)128 * 256 * 2);
    short* Wt1l = (short*)alloc((size_t)128 * 256 * 2);
    short* Wt2h = (short*)alloc((size_t)256 * 128 * 2);
    short* Wt2l = (short*)alloc((size_t)256 * 128 * 2);
    short* Wt3h = (short*)alloc((size_t)128 * 64 * 2);
    short* Wt3l = (short*)alloc((size_t)128 * 64 * 2);
    (void)ws_size; (void)n_in; (void)in_sizes; (void)out_size;

    hipMemsetAsync(cnt, 0, N_NODES * 4, stream);
    count_kernel<<<(E_TRAIN + 255) / 256, 256, 0, stream>>>(dst, cnt, E_TRAIN);
    int nb = (N_NODES + 255) / 256;  // 196
    scan1_kernel<<<nb, 256, 0, stream>>>(cnt, offs, bsum, dis, N_NODES);
    scan2_kernel<<<1, 256, 0, stream>>>(bsum, nb);
    scan3_kernel<<<nb, 256, 0, stream>>>(offs, bsum, cursor, N_NODES);
    fill_kernel<<<(E_TRAIN + 255) / 256, 256, 0, stream>>>(src, dst, cursor, csr, E_TRAIN);
    // after fill: offs[v] = start, cursor[v] = end

    const int WTOT = 128 * 256 + 256 * 128 + 128 * 64;
    wsplit_all_kernel<<<(WTOT + 255) / 256, 256, 0, stream>>>(
        W1, Wt1h, Wt1l, W2, Wt2h, Wt2l, W3, Wt3h, Wt3l);
    xconv_kernel<<<(N_NODES * 128 / 4 + 255) / 256, 256, 0, stream>>>(
        x, xb, N_NODES * 128 / 4);

    const int GB = (N_NODES + 127) / 128;     // 391 blocks of 128 rows
    const int AGG_BLOCKS = (N_NODES + 3) / 4; // 4 waves/block, 1 node/wave

    // layer 1 (agg-first): aggX = agg(xb) [F=128, fp32 out]; h1 = relu(aggX @ W1 + b1) [256 fp32]
    aggregate_bf16_kernel<128, false, false><<<AGG_BLOCKS, 256, 0, stream>>>(
        xb, aggX, dis, offs, cursor, csr, nullptr, N_NODES);
    gemm_fulln_kernel<256, true, false><<<GB, 512, 0, stream>>>(
        aggX, Wt1h, Wt1l, b1, h1, nullptr, N_NODES, 128);

    // layer 2 (gemm-first): xw2 = h1 @ W2 [128, bf16 out]; h2 = relu(agg(xw2b) + b2) [fp32]
    gemm_fulln_kernel<128, false, true><<<GB, 512, 0, stream>>>(
        h1, Wt2h, Wt2l, nullptr, nullptr, xw2b, N_NODES, 256);
    aggregate_bf16_kernel<128, true, true><<<AGG_BLOCKS, 256, 0, stream>>>(
        xw2b, h2, dis, offs, cursor, csr, b2, N_NODES);

    // layer 3 (gemm-first): xw3 = h2 @ W3 [64, bf16 out]; h3 = agg(xw3b) + b3 [fp32]
    gemm_fulln_kernel<64, false, true><<<GB, 512, 0, stream>>>(
        h2, Wt3h, Wt3l, nullptr, nullptr, xw3b, N_NODES, 128);
    aggregate_bf16_kernel<64, false, true><<<AGG_BLOCKS, 256, 0, stream>>>(
        xw3b, h3, dis, offs, cursor, csr, b3, N_NODES);

    // edge dots over h3 (64 features, fp32): 4 edges per wave
    const int DOT_WAVES = (E_POS + E_NEG + 3) / 4;            // 100000 waves
    dot_kernel<<<(DOT_WAVES + 3) / 4, 256, 0, stream>>>(h3, pos, neg, out);
}

// Round 14
// 377.884 us; speedup vs baseline: 1.4065x; 1.0452x over previous
//
#include <hip/hip_runtime.h>
#include <math.h>

#define N_NODES 50000
#define E_TRAIN 800000
#define E_POS 200000
#define E_NEG 200000

// ---------------- degree / CSR build ----------------

__global__ void count_kernel(const int* __restrict__ dst, int* __restrict__ cnt, int e) {
    int i = blockIdx.x * blockDim.x + threadIdx.x;
    if (i < e) atomicAdd(&cnt[dst[i]], 1);
}

// scan1 + dis fused: block-level exclusive scan of cnt, plus dis = rsqrt(deg+1)
__global__ void scan1_kernel(const int* __restrict__ cnt, int* __restrict__ offs,
                             int* __restrict__ bsum, float* __restrict__ dis, int n) {
    __shared__ int s[256];
    int i = blockIdx.x * 256 + threadIdx.x;
    int c = (i < n) ? cnt[i] : 0;
    if (i < n) dis[i] = 1.0f / sqrtf((float)(c + 1));  // +1 self loop
    s[threadIdx.x] = c;
    __syncthreads();
    for (int d = 1; d < 256; d <<= 1) {
        int t = 0;
        if ((int)threadIdx.x >= d) t = s[threadIdx.x - d];
        __syncthreads();
        if ((int)threadIdx.x >= d) s[threadIdx.x] += t;
        __syncthreads();
    }
    if (i < n) offs[i] = s[threadIdx.x] - c;  // exclusive
    if (threadIdx.x == 255) bsum[blockIdx.x] = s[255];
}

__global__ void scan2_kernel(int* __restrict__ bsum, int nb) {
    __shared__ int s[256];
    int t = threadIdx.x;
    int v = (t < nb) ? bsum[t] : 0;
    s[t] = v;
    __syncthreads();
    for (int d = 1; d < 256; d <<= 1) {
        int u = 0;
        if (t >= d) u = s[t - d];
        __syncthreads();
        if (t >= d) s[t] += u;
        __syncthreads();
    }
    if (t < nb) bsum[t] = s[t] - v;  // exclusive
}

__global__ void scan3_kernel(int* __restrict__ offs, const int* __restrict__ bsum,
                             int* __restrict__ cursor, int n) {
    int i = blockIdx.x * 256 + threadIdx.x;   // blockDim must be 256
    if (i < n) { int o = offs[i] + bsum[i >> 8]; offs[i] = o; cursor[i] = o; }
}

// csr entries are ushort: src node ids < 50000 < 65536
__global__ void fill_kernel(const int* __restrict__ src, const int* __restrict__ dst,
                            int* __restrict__ cursor, unsigned short* __restrict__ csr_src, int e) {
    int i = blockIdx.x * blockDim.x + threadIdx.x;
    if (i < e) {
        int p = atomicAdd(&cursor[dst[i]], 1);
        csr_src[p] = (unsigned short)src[i];
    }
}

// ---------------- bf16 helpers ----------------

__device__ inline void split_bf16(float f, short& h, short& l) {
    unsigned u = __float_as_uint(f);
    h = (short)(u >> 16);
    float rem = f - __uint_as_float(u & 0xFFFF0000u);
    l = (short)(__float_as_uint(rem) >> 16);
}

__device__ inline unsigned short f2bf_rne(float f) {
    unsigned u = __float_as_uint(f);
    unsigned r = u + 0x7FFFu + ((u >> 16) & 1u);
    return (unsigned short)(r >> 16);
}

__device__ inline float bf2f(unsigned short h) {
    return __uint_as_float(((unsigned)h) << 16);
}

// all three weights -> transposed hi/lo bf16 in one launch
__global__ void wsplit_all_kernel(const float* __restrict__ W1, short* __restrict__ W1h, short* __restrict__ W1l,
                                  const float* __restrict__ W2, short* __restrict__ W2h, short* __restrict__ W2l,
                                  const float* __restrict__ W3, short* __restrict__ W3h, short* __restrict__ W3l) {
    int i = blockIdx.x * blockDim.x + threadIdx.x;
    const float* W; short *Wh, *Wl; int K, N;
    if (i < 128 * 256) { W = W1; Wh = W1h; Wl = W1l; K = 128; N = 256; }
    else if (i < 128 * 256 + 256 * 128) { i -= 128 * 256; W = W2; Wh = W2h; Wl = W2l; K = 256; N = 128; }
    else if (i < 128 * 256 + 256 * 128 + 128 * 64) { i -= 128 * 256 + 256 * 128; W = W3; Wh = W3h; Wl = W3l; K = 128; N = 64; }
    else return;
    int k = i / N, n = i - k * N;
    short h, l;
    split_bf16(W[i], h, l);
    Wh[(size_t)n * K + k] = h;
    Wl[(size_t)n * K + k] = l;
}

// x (fp32) -> bf16 RNE gather table
__global__ void xconv_kernel(const float* __restrict__ x, unsigned short* __restrict__ xb, int n4) {
    int i = blockIdx.x * blockDim.x + threadIdx.x;
    if (i < n4) {
        float4 v = ((const float4*)x)[i];
        ushort4 o;
        o.x = f2bf_rne(v.x); o.y = f2bf_rne(v.y);
        o.z = f2bf_rne(v.z); o.w = f2bf_rne(v.w);
        ((ushort4*)xb)[i] = o;
    }
}

// ---------------- MFMA GEMM: 512 threads, 128 rows x full N, A streamed, B in LDS ----------------
// (R11 structure, proven: 8 waves/block, register-prefetch, transpose epilogue.)
// OBF: emit C as bf16 RNE (ushort) for gather consumers; else fp32.

typedef short bf16x8 __attribute__((ext_vector_type(8)));
typedef float f32x4 __attribute__((ext_vector_type(4)));

template<int BN, bool BR, bool OBF>
__global__ __launch_bounds__(512) void gemm_fulln_kernel(
        const float* __restrict__ A,
        const short* __restrict__ Bth, const short* __restrict__ Btl,
        const float* __restrict__ bias, float* __restrict__ C,
        unsigned short* __restrict__ Cb,
        int M, int K) {
    constexpr int NI = BN / 16;              // 16x16 tiles per wave
    constexpr int BCH = BN * 4;              // int4 chunks per B array per k-tile
    constexpr int BP = (BCH + 511) / 512;    // chunks per thread
    constexpr size_t BSZ = (size_t)2 * BN * 40 * 2;   // hi+lo, stride 40 shorts
    constexpr size_t TSZ = (size_t)8 * 16 * 68 * 4;   // 8-wave transpose buffer
    __shared__ __align__(16) char smem[BSZ > TSZ ? BSZ : TSZ];
    short* Bhi = (short*)smem;
    short* Blo = (short*)(smem + (size_t)BN * 40 * 2);
    float* tr  = (float*)smem;               // aliased after final barrier

    int tid = threadIdx.x;
    int lane = tid & 63;
    int wv = tid >> 6;                       // 0..7
    int brow = blockIdx.x * 128;
    int m_lane = lane & 15;
    int kgrp = lane >> 4;                    // 0..3

    int myrow = brow + wv * 16 + m_lane;
    if (myrow >= M) myrow = M - 1;           // clamp; garbage rows discarded at store
    const float* Ap = &A[(size_t)myrow * K + kgrp * 8];

    f32x4 acc[NI];
    #pragma unroll
    for (int i = 0; i < NI; i++) acc[i] = (f32x4){0.f, 0.f, 0.f, 0.f};

    int4 bhReg[BP], blReg[BP];
    float4 aN0, aN1, aC0, aC1;

    auto loadB = [&](int k0) {
        #pragma unroll
        for (int p = 0; p < BP; p++) {
            int idx = p * 512 + tid;
            if (idx < BCH) {
                int col = idx >> 2;
                int kc = idx & 3;
                size_t o = (size_t)col * K + k0 + kc * 8;
                bhReg[p] = *(const int4*)&Bth[o];
                blReg[p] = *(const int4*)&Btl[o];
            }
        }
    };
    auto loadA = [&](int k0) {
        aN0 = *(const float4*)&Ap[k0];
        aN1 = *(const float4*)&Ap[k0 + 4];
    };

    loadB(0); loadA(0);

    for (int k0 = 0; k0 < K; k0 += 32) {
        aC0 = aN0; aC1 = aN1;
        #pragma unroll
        for (int p = 0; p < BP; p++) {
            int idx = p * 512 + tid;
            if (idx < BCH) {
                int col = idx >> 2;
                int kc = idx & 3;
                *(int4*)&Bhi[col * 40 + kc * 8] = bhReg[p];
                *(int4*)&Blo[col * 40 + kc * 8] = blReg[p];
            }
        }
        __syncthreads();

        if (k0 + 32 < K) { loadB(k0 + 32); loadA(k0 + 32); }  // overlaps MFMA phase

        bf16x8 ah, al;
        {
            short h, l;
            split_bf16(aC0.x, h, l); ah[0] = h; al[0] = l;
            split_bf16(aC0.y, h, l); ah[1] = h; al[1] = l;
            split_bf16(aC0.z, h, l); ah[2] = h; al[2] = l;
            split_bf16(aC0.w, h, l); ah[3] = h; al[3] = l;
            split_bf16(aC1.x, h, l); ah[4] = h; al[4] = l;
            split_bf16(aC1.y, h, l); ah[5] = h; al[5] = l;
            split_bf16(aC1.z, h, l); ah[6] = h; al[6] = l;
            split_bf16(aC1.w, h, l); ah[7] = h; al[7] = l;
        }
        #pragma unroll
        for (int ni = 0; ni < NI; ni++) {
            int boff = (ni * 16 + m_lane) * 40 + kgrp * 8;
            bf16x8 bh = *(const bf16x8*)&Bhi[boff];
            bf16x8 bl = *(const bf16x8*)&Blo[boff];
            acc[ni] = __builtin_amdgcn_mfma_f32_16x16x32_bf16(ah, bh, acc[ni], 0, 0, 0);
            acc[ni] = __builtin_amdgcn_mfma_f32_16x16x32_bf16(al, bh, acc[ni], 0, 0, 0);
            acc[ni] = __builtin_amdgcn_mfma_f32_16x16x32_bf16(ah, bl, acc[ni], 0, 0, 0);
        }
        __syncthreads();
    }

    // epilogue: acc col = ni*16 + m_lane, local row = kgrp*4 + reg.
    // Chunks of 4 ni (64 cols): wave-local LDS transpose, then coalesced stores.
    #pragma unroll
    for (int c = 0; c < NI / 4; c++) {
        #pragma unroll
        for (int q = 0; q < 4; q++) {
            int ni = c * 4 + q;
            float bb = 0.f;
            if (BR) bb = bias[ni * 16 + m_lane];
            #pragma unroll
            for (int reg = 0; reg < 4; reg++) {
                float v = acc[ni][reg];
                if (BR) v = fmaxf(v + bb, 0.f);
                tr[wv * 1088 + (kgrp * 4 + reg) * 68 + q * 16 + m_lane] = v;
            }
        }
        // same-wave LDS RAW: in-order DS pipe + compiler lgkmcnt; no barrier needed
        #pragma unroll
        for (int j = 0; j < 4; j++) {
            int r = (lane >> 4) + j * 4;
            int g = lane & 15;
            float4 v = *(const float4*)&tr[wv * 1088 + r * 68 + g * 4];
            int row = brow + wv * 16 + r;
            if (row < M) {
                if (OBF) {
                    ushort4 o;
                    o.x = f2bf_rne(v.x); o.y = f2bf_rne(v.y);
                    o.z = f2bf_rne(v.z); o.w = f2bf_rne(v.w);
                    *(ushort4*)&Cb[(size_t)row * BN + c * 64 + g * 4] = o;
                } else {
                    *(float4*)&C[(size_t)row * BN + c * 64 + g * 4] = v;
                }
            }
        }
    }
}

// ---------------- aggregation over bf16 gather table (ushort csr) ----------------
// out[v] = sum_in xb[u]*dis[u]*dis[v] + xb[v]*dis[v]^2 (+ b, relu), fp32 accumulate/output.
// 16-edge batches: 16 independent csr->dis->gather chains in flight per wave.

template<int F, bool RELU, bool BIAS>
__global__ void aggregate_bf16_kernel(const unsigned short* __restrict__ xb,
                                      float* __restrict__ out,
                                      const float* __restrict__ dis,
                                      const int* __restrict__ starts,
                                      const int* __restrict__ ends,
                                      const unsigned short* __restrict__ csr_src,
                                      const float* __restrict__ bias,
                                      int n) {
    int wave = (blockIdx.x * blockDim.x + threadIdx.x) >> 6;
    int lane = threadIdx.x & 63;
    if (wave >= n) return;
    int v = wave;
    constexpr int VPT = F / 64;
    float dv = dis[v];
    float acc[VPT];
    if constexpr (VPT == 2) {
        ushort2 sv = *(const ushort2*)&xb[(size_t)v * F + lane * 2];
        acc[0] = bf2f(sv.x) * dv * dv;
        acc[1] = bf2f(sv.y) * dv * dv;
    } else {
        acc[0] = bf2f(xb[(size_t)v * F + lane]) * dv * dv;
    }
    int s = starts[v], e = ends[v];
    int p = s;
    for (; p + 16 <= e; p += 16) {
        int u[16];
        #pragma unroll
        for (int q = 0; q < 16; q++) u[q] = csr_src[p + q];
        float w[16];
        #pragma unroll
        for (int q = 0; q < 16; q++) w[q] = dis[u[q]] * dv;
        if constexpr (VPT == 2) {
            ushort2 g[16];
            #pragma unroll
            for (int q = 0; q < 16; q++)
                g[q] = *(const ushort2*)&xb[(size_t)u[q] * F + lane * 2];
            #pragma unroll
            for (int q = 0; q < 16; q++) {
                acc[0] += bf2f(g[q].x) * w[q];
                acc[1] += bf2f(g[q].y) * w[q];
            }
        } else {
            unsigned short g[16];
            #pragma unroll
            for (int q = 0; q < 16; q++)
                g[q] = xb[(size_t)u[q] * F + lane];
            #pragma unroll
            for (int q = 0; q < 16; q++) acc[0] += bf2f(g[q]) * w[q];
        }
    }
    for (; p + 8 <= e; p += 8) {
        int u[8];
        #pragma unroll
        for (int q = 0; q < 8; q++) u[q] = csr_src[p + q];
        float w[8];
        #pragma unroll
        for (int q = 0; q < 8; q++) w[q] = dis[u[q]] * dv;
        if constexpr (VPT == 2) {
            ushort2 g[8];
            #pragma unroll
            for (int q = 0; q < 8; q++)
                g[q] = *(const ushort2*)&xb[(size_t)u[q] * F + lane * 2];
            #pragma unroll
            for (int q = 0; q < 8; q++) {
                acc[0] += bf2f(g[q].x) * w[q];
                acc[1] += bf2f(g[q].y) * w[q];
            }
        } else {
            unsigned short g[8];
            #pragma unroll
            for (int q = 0; q < 8; q++)
                g[q] = xb[(size_t)u[q] * F + lane];
            #pragma unroll
            for (int q = 0; q < 8; q++) acc[0] += bf2f(g[q]) * w[q];
        }
    }
    for (; p < e; p++) {
        int u = csr_src[p];
        float w = dis[u] * dv;
        if constexpr (VPT == 2) {
            ushort2 g = *(const ushort2*)&xb[(size_t)u * F + lane * 2];
            acc[0] += bf2f(g.x) * w;
            acc[1] += bf2f(g.y) * w;
        } else {
            acc[0] += bf2f(xb[(size_t)u * F + lane]) * w;
        }
    }
    {
        float* o = &out[(size_t)v * F + lane * VPT];
        #pragma unroll
        for (int i = 0; i < VPT; i++) {
            float r = acc[i];
            if (BIAS) r += bias[lane * VPT + i];
            if (RELU) r = fmaxf(r, 0.f);
            o[i] = r;
        }
    }
}

// ---------------- edge dot products: 16 lanes per edge, 4 edges per wave ----------------

__global__ void dot_kernel(const float* __restrict__ h,
                           const int* __restrict__ pos, const int* __restrict__ neg,
                           float* __restrict__ out) {
    int gw = (blockIdx.x * blockDim.x + threadIdx.x) >> 6;
    int lane = threadIdx.x & 63;
    int sub = lane >> 4;          // edge within wave (0..3)
    int pl = lane & 15;           // float4 position within row
    int e = gw * 4 + sub;
    if (e >= E_POS + E_NEG) return;
    int i0, i1;
    if (e < E_POS) { i0 = pos[e]; i1 = pos[E_POS + e]; }
    else { int t = e - E_POS; i0 = neg[t]; i1 = neg[E_NEG + t]; }
    float4 a = *(const float4*)&h[(size_t)i0 * 64 + pl * 4];
    float4 b = *(const float4*)&h[(size_t)i1 * 64 + pl * 4];
    float v = a.x * b.x + a.y * b.y + a.z * b.z + a.w * b.w;
    v += __shfl_xor(v, 1, 64);
    v += __shfl_xor(v, 2, 64);
    v += __shfl_xor(v, 4, 64);
    v += __shfl_xor(v, 8, 64);
    if (pl == 0) out[e] = v;
}

// ---------------- launch ----------------

extern "C" void kernel_launch(void* const* d_in, const int* in_sizes, int n_in,
                              void* d_out, int out_size, void* d_ws, size_t ws_size,
                              hipStream_t stream) {
    const float* x  = (const float*)d_in[0];
    const int* tei  = (const int*)d_in[1];
    const int* pos  = (const int*)d_in[2];
    const int* neg  = (const int*)d_in[3];
    const float* W1 = (const float*)d_in[4];
    const float* b1 = (const float*)d_in[5];
    const float* W2 = (const float*)d_in[6];
    const float* b2 = (const float*)d_in[7];
    const float* W3 = (const float*)d_in[8];
    const float* b3 = (const float*)d_in[9];
    float* out = (float*)d_out;

    const int* src = tei;
    const int* dst = tei + E_TRAIN;

    char* ws = (char*)d_ws;
    size_t off = 0;
    auto alloc = [&](size_t bytes) -> void* {
        void* p = ws + off;
        off = (off + bytes + 255) & ~(size_t)255;
        return p;
    };
    unsigned short* xb   = (unsigned short*)alloc((size_t)N_NODES * 128 * 2);  // x bf16
    float* aggX          = (float*)alloc((size_t)N_NODES * 128 * 4);
    float* h1            = (float*)alloc((size_t)N_NODES * 256 * 4);
    unsigned short* xw2b = (unsigned short*)alloc((size_t)N_NODES * 128 * 2);
    float* h2            = (float*)alloc((size_t)N_NODES * 128 * 4);
    unsigned short* xw3b = (unsigned short*)alloc((size_t)N_NODES * 64 * 2);
    float* h3            = (float*)alloc((size_t)N_NODES * 64 * 4);
    float* dis  = (float*)alloc(N_NODES * 4);
    int* cnt    = (int*)alloc(N_NODES * 4);
    int* offs   = (int*)alloc(N_NODES * 4);
    int* cursor = (int*)alloc(N_NODES * 4);
    int* bsum   = (int*)alloc(256 * 4);
    unsigned short* csr = (unsigned short*)alloc((size_t)E_TRAIN * 2);
    short* Wt1h = (short*)alloc((size_t)128 * 256 * 2);
    short* Wt1l = (short*)alloc((size_t)128 * 256 * 2);
    short* Wt2h = (short*)alloc((size_t)256 * 128 * 2);
    short* Wt2l = (short*)alloc((size_t)256 * 128 * 2);
    short* Wt3h = (short*)alloc((size_t)128 * 64 * 2);
    short* Wt3l = (short*)alloc((size_t)128 * 64 * 2);
    (void)ws_size; (void)n_in; (void)in_sizes; (void)out_size;

    hipMemsetAsync(cnt, 0, N_NODES * 4, stream);
    count_kernel<<<(E_TRAIN + 255) / 256, 256, 0, stream>>>(dst, cnt, E_TRAIN);
    int nb = (N_NODES + 255) / 256;  // 196
    scan1_kernel<<<nb, 256, 0, stream>>>(cnt, offs, bsum, dis, N_NODES);
    scan2_kernel<<<1, 256, 0, stream>>>(bsum, nb);
    scan3_kernel<<<nb, 256, 0, stream>>>(offs, bsum, cursor, N_NODES);
    fill_kernel<<<(E_TRAIN + 255) / 256, 256, 0, stream>>>(src, dst, cursor, csr, E_TRAIN);
    // after fill: offs[v] = start, cursor[v] = end

    const int WTOT = 128 * 256 + 256 * 128 + 128 * 64;
    wsplit_all_kernel<<<(WTOT + 255) / 256, 256, 0, stream>>>(
        W1, Wt1h, Wt1l, W2, Wt2h, Wt2l, W3, Wt3h, Wt3l);
    xconv_kernel<<<(N_NODES * 128 / 4 + 255) / 256, 256, 0, stream>>>(
        x, xb, N_NODES * 128 / 4);

    const int GB = (N_NODES + 127) / 128;     // 391 blocks of 128 rows
    const int AGG_BLOCKS = (N_NODES + 3) / 4; // 4 waves/block, 1 node/wave

    // layer 1 (agg-first): aggX = agg(xb) [F=128, fp32 out]; h1 = relu(aggX @ W1 + b1) [256 fp32]
    aggregate_bf16_kernel<128, false, false><<<AGG_BLOCKS, 256, 0, stream>>>(
        xb, aggX, dis, offs, cursor, csr, nullptr, N_NODES);
    gemm_fulln_kernel<256, true, false><<<GB, 512, 0, stream>>>(
        aggX, Wt1h, Wt1l, b1, h1, nullptr, N_NODES, 128);

    // layer 2 (gemm-first): xw2 = h1 @ W2 [128, bf16 out]; h2 = relu(agg(xw2b) + b2) [fp32]
    gemm_fulln_kernel<128, false, true><<<GB, 512, 0, stream>>>(
        h1, Wt2h, Wt2l, nullptr, nullptr, xw2b, N_NODES, 256);
    aggregate_bf16_kernel<128, true, true><<<AGG_BLOCKS, 256, 0, stream>>>(
        xw2b, h2, dis, offs, cursor, csr, b2, N_NODES);

    // layer 3 (gemm-first): xw3 = h2 @ W3 [64, bf16 out]; h3 = agg(xw3b) + b3 [fp32]
    gemm_fulln_kernel<64, false, true><<<GB, 512, 0, stream>>>(
        h2, Wt3h, Wt3l, nullptr, nullptr, xw3b, N_NODES, 128);
    aggregate_bf16_kernel<64, false, true><<<AGG_BLOCKS, 256, 0, stream>>>(
        xw3b, h3, dis, offs, cursor, csr, b3, N_NODES);

    // edge dots over h3 (64 features, fp32): 4 edges per wave
    const int DOT_WAVES = (E_POS + E_NEG + 3) / 4;            // 100000 waves
    dot_kernel<<<(DOT_WAVES + 3) / 4, 256, 0, stream>>>(h3, pos, neg, out);
}